// Round 4
// baseline (554.546 us; speedup 1.0000x reference)
//
#include <hip/hip_runtime.h>

// Res_MCNN_branch2 on gfx950 — all convs via f16 MFMA implicit-GEMM (16x16x32).
// conv1: K = kx*4+c (C=3 padded to 4, kx padded to 8), K-steps = 7 ky.
//        Weights (all taps, 14.3 KB) + input tile staged once -> barrier-free K-loop.
// conv1/conv2 pooling via PHASE-MAPPED N-tiles: j = group*4 + (phy*2+phx), so the
//        4 pool partners of a pooled pixel sit in the same lane across 4 j-tiles.
//        Pool = 3 register fmaxf, no shfl, all 64 lanes store.
// conv2: K = 25 taps x 32c -> P2 f16 NHWC64.   conv3: K = 25x64 -> X3 f16 NHWC32.
// conv4: K = 25x32 -> X4 fp32 NHWC10.
// conv5: 1x1 conv + gray residual (bilinear 4x == 2x2 avg at rows/cols {4i+1,4i+2}).

typedef _Float16 half_t;
typedef _Float16 half8 __attribute__((ext_vector_type(8)));
typedef float floatx4 __attribute__((ext_vector_type(4)));

#define IN_H 768
#define IN_W 1024
#define P1H 384
#define P1W 512
#define P2H 192
#define P2W 256

// workspace offsets (bytes)
#define OFF_P2 0ULL                 // f16 [8][192][256][64]  = 50,331,648
#define OFF_P1 50331648ULL          // f16 [8][384][512][32]  = 100,663,296
#define OFF_X3 50331648ULL          // reuse P1 region after conv2
#define OFF_X4 0ULL                 // fp32 [8][192][256][10] reuse P2 region after conv3
#define OFF_W2 150994944ULL         // f16 [25][48][32] = 76,800 el
#define OFF_W3 151072768ULL         // f16 [25][32][64] = 102,400 el
#define OFF_W4 151175168ULL         // f16 [25][16][32] = 25,600 el
#define OFF_W1 151226368ULL         // f16 [7][32][32]  = 7,168 el

union PK4 { half_t h[4]; uint2 u; };
union U8 { half8 v; uint2 u[2]; };

// ---------------- weight pre-pack (fp32 OIHW -> f16 packed) ----------------
__global__ __launch_bounds__(256) void pack_weights(
    const float* __restrict__ w2, const float* __restrict__ w3,
    const float* __restrict__ w4, const float* __restrict__ w1,
    half_t* __restrict__ wp2, half_t* __restrict__ wp3, half_t* __restrict__ wp4,
    half_t* __restrict__ wp1)
{
  int t = blockIdx.x * 256 + threadIdx.x;
  if (t < 38400) {                       // conv2: [25][48][32]
    int tap = t / 1536, r = t % 1536, oc = r >> 5, c = r & 31;
    float v = (oc < 40 && c < 20) ? w2[(oc * 20 + c) * 25 + tap] : 0.f;
    wp2[t] = (half_t)v;
  } else if (t < 89600) {                // conv3: [25][32][64]
    int u = t - 38400;
    int tap = u / 2048, r = u % 2048, oc = r >> 6, c = r & 63;
    float v = (oc < 20 && c < 40) ? w3[(oc * 40 + c) * 25 + tap] : 0.f;
    wp3[u] = (half_t)v;
  } else if (t < 102400) {               // conv4: [25][16][32]
    int u = t - 89600;
    int tap = u / 512, r = u % 512, oc = r >> 5, c = r & 31;
    float v = (oc < 10 && c < 20) ? w4[(oc * 20 + c) * 25 + tap] : 0.f;
    wp4[u] = (half_t)v;
  } else if (t < 109568) {               // conv1: [7][32][32], k = kx*4+c
    int u = t - 102400;
    int ky = u / 1024, r = u % 1024, oc = r >> 5, k = r & 31;
    int kx = k >> 2, c = k & 3;
    float v = (oc < 20 && c < 3 && kx < 7) ? w1[((oc * 3 + c) * 7 + ky) * 7 + kx] : 0.f;
    wp1[u] = (half_t)v;
  }
}

// ---------------- conv1 (3->20, 7x7, pad 3) MFMA + relu + pool -> P1 f16 NHWC32 ----------------
// conv tile 16x32 px -> pooled 8x16; oc padded to 32 (2 M-tiles).
// j = g*4 + (phy*2+phx): N-columns are 16 pooled px at pool-phase (phy,phx),
// pooled row pr = wv*2+g, pooled col = nl. Pool = register max over j-phases.
__global__ __launch_bounds__(256) void conv1_mfma(
    const float* __restrict__ in, const half_t* __restrict__ wp,
    const float* __restrict__ bias, half_t* __restrict__ P1)
{
  __shared__ __align__(16) half_t ltile[22 * 40 * 4];   // 7040 B, row stride 40 px
  __shared__ __align__(16) half_t wlds[7 * 32 * 32];    // 14336 B, all taps
  const int b = blockIdx.z, ty0 = blockIdx.y * 16, tx0 = blockIdx.x * 32;
  const int tid = threadIdx.x;

  for (int i = tid; i < 896; i += 256)
    *(uint4*)(wlds + i * 8) = *(const uint4*)(wp + i * 8);

  const float* p0 = in + (size_t)b * 3 * IN_H * IN_W;
  for (int i = tid; i < 880; i += 256) {          // 22 rows x 40 cols (38 real + 2 zero)
    int r = i / 40, c = i - r * 40;
    int gy = ty0 - 3 + r, gx = tx0 - 3 + c;
    float v0 = 0.f, v1 = 0.f, v2 = 0.f;
    if (c < 38 && gy >= 0 && gy < IN_H && gx >= 0 && gx < IN_W) {
      size_t o = (size_t)gy * IN_W + gx;
      v0 = p0[o];
      v1 = p0[o + IN_H * IN_W];
      v2 = p0[o + 2 * IN_H * IN_W];
    }
    PK4 pk;
    pk.h[0] = (half_t)v0; pk.h[1] = (half_t)v1;
    pk.h[2] = (half_t)v2; pk.h[3] = (half_t)0.f;
    *(uint2*)(ltile + (r * 40 + c) * 4) = pk.u;
  }
  __syncthreads();

  const int wv = tid >> 6, ln = tid & 63, q = ln >> 4, nl = ln & 15;
  int baseB[8];
  #pragma unroll
  for (int j = 0; j < 8; ++j) {
    int g = j >> 2, ph = j & 3, phy = ph >> 1, phx = ph & 1;
    int ly = 2 * (wv * 2 + g) + phy;              // conv row 0..15
    int lx = 2 * nl + phx;                        // conv col 0..31
    baseB[j] = (ly * 40 + lx + 2 * q) * 4;        // halves; +ky*160 per K-step
  }
  const int aoff = nl * 32 + q * 8;
  floatx4 acc[2][8];
  #pragma unroll
  for (int mt = 0; mt < 2; ++mt)
    #pragma unroll
    for (int j = 0; j < 8; ++j) acc[mt][j] = (floatx4){0.f, 0.f, 0.f, 0.f};

  for (int ky = 0; ky < 7; ++ky) {
    const half_t* wb = wlds + ky * 1024;
    half8 A0 = *(const half8*)(wb + aoff);
    half8 A1 = *(const half8*)(wb + 512 + aoff);
    const half_t* tb = ltile + ky * 160;
    #pragma unroll
    for (int j = 0; j < 8; ++j) {
      U8 B;
      B.u[0] = *(const uint2*)(tb + baseB[j]);
      B.u[1] = *(const uint2*)(tb + baseB[j] + 4);
      acc[0][j] = __builtin_amdgcn_mfma_f32_16x16x32_f16(A0, B.v, acc[0][j], 0, 0, 0);
      acc[1][j] = __builtin_amdgcn_mfma_f32_16x16x32_f16(A1, B.v, acc[1][j], 0, 0, 0);
    }
  }

  floatx4 bv[2];
  #pragma unroll
  for (int mt = 0; mt < 2; ++mt)
    #pragma unroll
    for (int r = 0; r < 4; ++r) {
      int oc = mt * 16 + q * 4 + r;
      bv[mt][r] = (oc < 20) ? bias[oc] : 0.f;
    }
  const int pr0 = (ty0 >> 1) + wv * 2;
  const int pc = (tx0 >> 1) + nl;
  #pragma unroll
  for (int g = 0; g < 2; ++g) {
    size_t pxbase = (((size_t)b * P1H + pr0 + g) * P1W + pc) * 32;
    #pragma unroll
    for (int mt = 0; mt < 2; ++mt) {
      PK4 pk;
      #pragma unroll
      for (int r = 0; r < 4; ++r) {
        float x = fmaxf(fmaxf(acc[mt][g * 4 + 0][r], acc[mt][g * 4 + 1][r]),
                        fmaxf(acc[mt][g * 4 + 2][r], acc[mt][g * 4 + 3][r]));
        pk.h[r] = (half_t)fmaxf(x + bv[mt][r], 0.f);   // oc>=20: 0+0 -> 0 pad
      }
      *(uint2*)(P1 + pxbase + mt * 16 + q * 4) = pk.u;
    }
  }
}

// ---------------- conv2 (20->40, 5x5) MFMA + relu + pool -> P2 f16 NHWC64 ----------------
// Same phase-mapped pooling: conv tile 16x32 -> pooled 8x16, 3 M-tiles (oc 48).
__global__ __launch_bounds__(256) void conv2_mfma(
    const half_t* __restrict__ P1, const half_t* __restrict__ wp,
    const float* __restrict__ bias, half_t* __restrict__ P2)
{
  __shared__ __align__(16) half_t lin[20][36][32];   // 46080 B
  __shared__ __align__(16) half_t wlds[2][48][32];   // 6144 B
  const int b = blockIdx.z, ty0 = blockIdx.y * 16, tx0 = blockIdx.x * 32;
  const int tid = threadIdx.x;
  for (int i = tid; i < 2880; i += 256) {
    int px = i >> 2, part = i & 3;
    int row = px / 36, col = px - row * 36;
    int gy = ty0 - 2 + row, gx = tx0 - 2 + col;
    uint4 v = make_uint4(0, 0, 0, 0);
    if (gy >= 0 && gy < P1H && gx >= 0 && gx < P1W)
      v = *(const uint4*)(P1 + (((size_t)b * P1H + gy) * P1W + gx) * 32 + part * 8);
    *(uint4*)&lin[row][col][part * 8] = v;
  }
  if (tid < 192)
    *(uint4*)(&wlds[0][0][0] + tid * 8) = *(const uint4*)(wp + tid * 8);
  __syncthreads();

  const int wv = tid >> 6, ln = tid & 63, q = ln >> 4, nl = ln & 15;
  int baseB[8];
  #pragma unroll
  for (int j = 0; j < 8; ++j) {
    int g = j >> 2, ph = j & 3, phy = ph >> 1, phx = ph & 1;
    int ly = 2 * (wv * 2 + g) + phy;
    int lx = 2 * nl + phx;
    baseB[j] = (ly * 36 + lx) * 32 + q * 8;
  }
  const int aoff = nl * 32 + q * 8;
  floatx4 acc[3][8];
  #pragma unroll
  for (int mt = 0; mt < 3; ++mt)
    #pragma unroll
    for (int j = 0; j < 8; ++j) acc[mt][j] = (floatx4){0.f, 0.f, 0.f, 0.f};

  for (int tap = 0; tap < 25; ++tap) {
    const int bufc = tap & 1;
    uint4 wpre;
    const bool pre = (tap < 24) && (tid < 192);
    if (pre) wpre = *(const uint4*)(wp + (tap + 1) * 1536 + tid * 8);
    const int ky = tap / 5, kx = tap - (tap / 5) * 5;
    const int tapoff = (ky * 36 + kx) * 32;
    const half_t* wb = &wlds[bufc][0][0];
    half8 A[3];
    #pragma unroll
    for (int mt = 0; mt < 3; ++mt)
      A[mt] = *(const half8*)(wb + mt * 512 + aoff);
    #pragma unroll
    for (int g = 0; g < 2; ++g) {
      half8 B[4];
      #pragma unroll
      for (int jj = 0; jj < 4; ++jj)
        B[jj] = *(const half8*)(&lin[0][0][0] + baseB[g * 4 + jj] + tapoff);
      #pragma unroll
      for (int mt = 0; mt < 3; ++mt)
        #pragma unroll
        for (int jj = 0; jj < 4; ++jj)
          acc[mt][g * 4 + jj] = __builtin_amdgcn_mfma_f32_16x16x32_f16(
              A[mt], B[jj], acc[mt][g * 4 + jj], 0, 0, 0);
    }
    if (pre) *(uint4*)(&wlds[1 - bufc][0][0] + tid * 8) = wpre;
    __syncthreads();
  }

  floatx4 bv[3];
  #pragma unroll
  for (int mt = 0; mt < 3; ++mt)
    #pragma unroll
    for (int r = 0; r < 4; ++r) {
      int oc = mt * 16 + q * 4 + r;
      bv[mt][r] = (oc < 40) ? bias[oc] : 0.f;
    }
  const int pr0 = (ty0 >> 1) + wv * 2;
  const int pc = (tx0 >> 1) + nl;
  #pragma unroll
  for (int g = 0; g < 2; ++g) {
    size_t pxbase = (((size_t)b * P2H + pr0 + g) * P2W + pc) * 64;
    #pragma unroll
    for (int mt = 0; mt < 3; ++mt) {
      PK4 pk;
      #pragma unroll
      for (int r = 0; r < 4; ++r) {
        float x = fmaxf(fmaxf(acc[mt][g * 4 + 0][r], acc[mt][g * 4 + 1][r]),
                        fmaxf(acc[mt][g * 4 + 2][r], acc[mt][g * 4 + 3][r]));
        pk.h[r] = (half_t)fmaxf(x + bv[mt][r], 0.f);
      }
      *(uint2*)(P2 + pxbase + mt * 16 + q * 4) = pk.u;
    }
    if (q < 2)
      *(uint4*)(P2 + pxbase + 48 + q * 8) = make_uint4(0, 0, 0, 0);  // oc 48..63 = 0
  }
}

// ---------------- conv3 (40->20, 5x5) MFMA + relu -> X3 f16 NHWC32 ----------------
__global__ __launch_bounds__(256) void conv3_mfma(
    const half_t* __restrict__ P2, const half_t* __restrict__ wp,
    const float* __restrict__ bias, half_t* __restrict__ X3)
{
  __shared__ __align__(16) half_t lin[12][36][64];   // 55296 B
  __shared__ __align__(16) half_t wlds[2][32][64];   // 8192 B
  const int b = blockIdx.z, ty0 = blockIdx.y * 8, tx0 = blockIdx.x * 32;
  const int tid = threadIdx.x;
  for (int i = tid; i < 3456; i += 256) {
    int px = i >> 3, part = i & 7;
    int row = px / 36, col = px - row * 36;
    int gy = ty0 - 2 + row, gx = tx0 - 2 + col;
    uint4 v = make_uint4(0, 0, 0, 0);
    if (gy >= 0 && gy < P2H && gx >= 0 && gx < P2W)
      v = *(const uint4*)(P2 + (((size_t)b * P2H + gy) * P2W + gx) * 64 + part * 8);
    *(uint4*)&lin[row][col][part * 8] = v;
  }
  *(uint4*)(&wlds[0][0][0] + tid * 8) = *(const uint4*)(wp + tid * 8);
  __syncthreads();

  const int wv = tid >> 6, ln = tid & 63, q = ln >> 4, nl = ln & 15;
  int baseB[4];
  #pragma unroll
  for (int j = 0; j < 4; ++j) {
    int nt = wv * 4 + j;
    int ly = nt >> 1, lx = (nt & 1) * 16 + nl;
    baseB[j] = (ly * 36 + lx) * 64 + q * 8;
  }
  const int aoff = nl * 64 + q * 8;
  floatx4 acc[2][4];
  #pragma unroll
  for (int mt = 0; mt < 2; ++mt)
    #pragma unroll
    for (int j = 0; j < 4; ++j) acc[mt][j] = (floatx4){0.f, 0.f, 0.f, 0.f};

  for (int tap = 0; tap < 25; ++tap) {
    const int bufc = tap & 1;
    uint4 wpre;
    const bool pre = (tap < 24);
    if (pre) wpre = *(const uint4*)(wp + (tap + 1) * 2048 + tid * 8);
    const int ky = tap / 5, kx = tap - (tap / 5) * 5;
    const half_t* wb = &wlds[bufc][0][0];
    #pragma unroll
    for (int cb = 0; cb < 2; ++cb) {
      const int tapoff = (ky * 36 + kx) * 64 + cb * 32;
      half8 A[2];
      #pragma unroll
      for (int mt = 0; mt < 2; ++mt)
        A[mt] = *(const half8*)(wb + mt * 1024 + cb * 32 + aoff);
      half8 B[4];
      #pragma unroll
      for (int jj = 0; jj < 4; ++jj)
        B[jj] = *(const half8*)(&lin[0][0][0] + baseB[jj] + tapoff);
      #pragma unroll
      for (int mt = 0; mt < 2; ++mt)
        #pragma unroll
        for (int jj = 0; jj < 4; ++jj)
          acc[mt][jj] = __builtin_amdgcn_mfma_f32_16x16x32_f16(
              A[mt], B[jj], acc[mt][jj], 0, 0, 0);
    }
    if (pre) *(uint4*)(&wlds[1 - bufc][0][0] + tid * 8) = wpre;
    __syncthreads();
  }

  floatx4 bv[2];
  #pragma unroll
  for (int mt = 0; mt < 2; ++mt)
    #pragma unroll
    for (int r = 0; r < 4; ++r) {
      int oc = mt * 16 + q * 4 + r;
      bv[mt][r] = (oc < 20) ? bias[oc] : 0.f;
    }
  #pragma unroll
  for (int j = 0; j < 4; ++j) {
    int nt = wv * 4 + j;
    int y = ty0 + (nt >> 1), x = tx0 + (nt & 1) * 16 + nl;
    size_t pxbase = (((size_t)b * P2H + y) * P2W + x) * 32;
    #pragma unroll
    for (int mt = 0; mt < 2; ++mt) {
      floatx4 v = acc[mt][j];
      PK4 pk;
      #pragma unroll
      for (int r = 0; r < 4; ++r) pk.h[r] = (half_t)fmaxf(v[r] + bv[mt][r], 0.f);
      *(uint2*)(X3 + pxbase + mt * 16 + q * 4) = pk.u;
    }
  }
}

// ---------------- conv4 (20->10, 5x5) MFMA + relu -> X4 fp32 NHWC10 ----------------
__global__ __launch_bounds__(256) void conv4_mfma(
    const half_t* __restrict__ X3, const half_t* __restrict__ wp,
    const float* __restrict__ bias, float* __restrict__ X4)
{
  __shared__ __align__(16) half_t lin[20][36][32];   // 46080 B
  __shared__ __align__(16) half_t wlds[2][16][32];   // 2048 B
  const int b = blockIdx.z, ty0 = blockIdx.y * 16, tx0 = blockIdx.x * 32;
  const int tid = threadIdx.x;
  for (int i = tid; i < 2880; i += 256) {
    int px = i >> 2, part = i & 3;
    int row = px / 36, col = px - row * 36;
    int gy = ty0 - 2 + row, gx = tx0 - 2 + col;
    uint4 v = make_uint4(0, 0, 0, 0);
    if (gy >= 0 && gy < P2H && gx >= 0 && gx < P2W)
      v = *(const uint4*)(X3 + (((size_t)b * P2H + gy) * P2W + gx) * 32 + part * 8);
    *(uint4*)&lin[row][col][part * 8] = v;
  }
  if (tid < 64)
    *(uint4*)(&wlds[0][0][0] + tid * 8) = *(const uint4*)(wp + tid * 8);
  __syncthreads();

  const int wv = tid >> 6, ln = tid & 63, q = ln >> 4, nl = ln & 15;
  int baseB[8];
  #pragma unroll
  for (int j = 0; j < 8; ++j) {
    int nt = wv * 8 + j;
    int ly = nt >> 1, lx = (nt & 1) * 16 + nl;
    baseB[j] = (ly * 36 + lx) * 32 + q * 8;
  }
  const int aoff = nl * 32 + q * 8;
  floatx4 acc[8];
  #pragma unroll
  for (int j = 0; j < 8; ++j) acc[j] = (floatx4){0.f, 0.f, 0.f, 0.f};

  for (int tap = 0; tap < 25; ++tap) {
    const int bufc = tap & 1;
    uint4 wpre;
    const bool pre = (tap < 24) && (tid < 64);
    if (pre) wpre = *(const uint4*)(wp + (tap + 1) * 512 + tid * 8);
    const int ky = tap / 5, kx = tap - (tap / 5) * 5;
    const int tapoff = (ky * 36 + kx) * 32;
    const half_t* wb = &wlds[bufc][0][0];
    half8 A = *(const half8*)(wb + aoff);
    #pragma unroll
    for (int j = 0; j < 8; ++j) {
      half8 B = *(const half8*)(&lin[0][0][0] + baseB[j] + tapoff);
      acc[j] = __builtin_amdgcn_mfma_f32_16x16x32_f16(A, B, acc[j], 0, 0, 0);
    }
    if (pre) *(uint4*)(&wlds[1 - bufc][0][0] + tid * 8) = wpre;
    __syncthreads();
  }

  float bv[4];
  #pragma unroll
  for (int r = 0; r < 4; ++r) {
    int oc = q * 4 + r;
    bv[r] = (oc < 10) ? bias[oc] : 0.f;
  }
  #pragma unroll
  for (int j = 0; j < 8; ++j) {
    int nt = wv * 8 + j;
    int y = ty0 + (nt >> 1), x = tx0 + (nt & 1) * 16 + nl;
    float* dst = X4 + (((size_t)b * P2H + y) * P2W + x) * 10;
    floatx4 v = acc[j];
    float r0 = fmaxf(v[0] + bv[0], 0.f), r1 = fmaxf(v[1] + bv[1], 0.f);
    float r2 = fmaxf(v[2] + bv[2], 0.f), r3 = fmaxf(v[3] + bv[3], 0.f);
    if (q < 2) {
      *(float2*)(dst + q * 4)     = make_float2(r0, r1);
      *(float2*)(dst + q * 4 + 2) = make_float2(r2, r3);
    } else if (q == 2) {
      *(float2*)(dst + 8) = make_float2(r0, r1);   // oc 8,9
    }
  }
}

// ---------------- conv5 (10->1, 1x1) + gray residual + relu ----------------
__global__ __launch_bounds__(256) void conv5_res(
    const float* __restrict__ X4, const float* __restrict__ w5,
    const float* __restrict__ b5, const float* __restrict__ in,
    float* __restrict__ out)
{
  const int idx = blockIdx.x * 256 + threadIdx.x;  // 0 .. 8*192*256-1
  const int j = idx & 255;
  const int bi = idx >> 8;
  const int i = bi % 192;
  const int b = bi / 192;
  const float* xp = X4 + (((size_t)b * P2H + i) * P2W + j) * 10;
  float sum = b5[0];
  #pragma unroll
  for (int c = 0; c < 10; ++c) sum += w5[c] * xp[c];
  const int r0 = 4 * i + 1, c0 = 4 * j + 1;
  float g = 0.f;
  #pragma unroll
  for (int ch = 0; ch < 3; ++ch) {
    const float coef = (ch == 0) ? 0.299f : ((ch == 1) ? 0.587f : 0.114f);
    const float* q = in + ((size_t)b * 3 + ch) * IN_H * IN_W;
    g += coef * (q[(size_t)r0 * IN_W + c0] + q[(size_t)r0 * IN_W + c0 + 1] +
                 q[(size_t)(r0 + 1) * IN_W + c0] + q[(size_t)(r0 + 1) * IN_W + c0 + 1]);
  }
  g *= 0.25f;
  out[idx] = fmaxf(sum + fmaxf(g, 0.f), 0.f);
}

extern "C" void kernel_launch(void* const* d_in, const int* in_sizes, int n_in,
                              void* d_out, int out_size, void* d_ws, size_t ws_size,
                              hipStream_t stream) {
  const float* input = (const float*)d_in[0];
  const float* w1 = (const float*)d_in[1];  const float* b1 = (const float*)d_in[2];
  const float* w2 = (const float*)d_in[3];  const float* b2 = (const float*)d_in[4];
  const float* w3 = (const float*)d_in[5];  const float* b3 = (const float*)d_in[6];
  const float* w4 = (const float*)d_in[7];  const float* b4 = (const float*)d_in[8];
  const float* w5 = (const float*)d_in[9];  const float* b5 = (const float*)d_in[10];
  float* out = (float*)d_out;
  char* ws = (char*)d_ws;

  half_t* P2h = (half_t*)(ws + OFF_P2);
  half_t* P1h = (half_t*)(ws + OFF_P1);
  half_t* X3h = (half_t*)(ws + OFF_X3);
  float*  X4f = (float*)(ws + OFF_X4);
  half_t* wp2 = (half_t*)(ws + OFF_W2);
  half_t* wp3 = (half_t*)(ws + OFF_W3);
  half_t* wp4 = (half_t*)(ws + OFF_W4);
  half_t* wp1 = (half_t*)(ws + OFF_W1);

  pack_weights<<<432, 256, 0, stream>>>(w2, w3, w4, w1, wp2, wp3, wp4, wp1);
  conv1_mfma<<<dim3(32, 48, 8), 256, 0, stream>>>(input, wp1, b1, P1h);
  conv2_mfma<<<dim3(16, 24, 8), 256, 0, stream>>>(P1h, wp2, b2, P2h);
  conv3_mfma<<<dim3(8, 24, 8), 256, 0, stream>>>(P2h, wp3, b3, X3h);
  conv4_mfma<<<dim3(8, 12, 8), 256, 0, stream>>>(X3h, wp4, b4, X4f);
  conv5_res<<<1536, 256, 0, stream>>>(X4f, w5, b5, input, out);
}

// Round 5
// 479.915 us; speedup vs baseline: 1.1555x; 1.1555x over previous
//
#include <hip/hip_runtime.h>

// Res_MCNN_branch2 on gfx950 — all convs via f16 MFMA implicit-GEMM (16x16x32).
// LDS BANK RULE (this round's fix): every record padded so record stride is a
// multiple of 16B but not 0 mod 128B: 32-half records -> 40 halves (20 dwords),
// 64-half records -> 72 halves (36 dwords). Stride-1 lane readers land 2-way
// (free); conv1/conv2's phase-mapped stride-2 readers land 4-way (was 16-way).
// conv1: K = kx*4+c, 7 barrier-free K-steps; phase-pooled epilogue -> P1 NHWC32.
// conv2: 25 taps x 32c, phase-pooled -> P2 NHWC64. conv3: 25x64 -> X3 NHWC32.
// conv4: 25x32 -> X4 fp32 NHWC10. conv5: 1x1 + gray residual (4x bilinear ==
// 2x2 avg at rows/cols {4i+1,4i+2}).

typedef _Float16 half_t;
typedef _Float16 half8 __attribute__((ext_vector_type(8)));
typedef float floatx4 __attribute__((ext_vector_type(4)));

#define IN_H 768
#define IN_W 1024
#define P1H 384
#define P1W 512
#define P2H 192
#define P2W 256

// workspace offsets (bytes)
#define OFF_P2 0ULL                 // f16 [8][192][256][64]  = 50,331,648
#define OFF_P1 50331648ULL          // f16 [8][384][512][32]  = 100,663,296
#define OFF_X3 50331648ULL          // reuse P1 region after conv2
#define OFF_X4 0ULL                 // fp32 [8][192][256][10] reuse P2 region after conv3
#define OFF_W2 150994944ULL         // f16 [25][48][32] = 76,800 el
#define OFF_W3 151072768ULL         // f16 [25][32][64] = 102,400 el
#define OFF_W4 151175168ULL         // f16 [25][16][32] = 25,600 el
#define OFF_W1 151226368ULL         // f16 [7][32][32]  = 7,168 el

union PK4 { half_t h[4]; uint2 u; };
union U8 { half8 v; uint2 u[2]; };

// ---------------- weight pre-pack (fp32 OIHW -> f16 packed, linear) ----------------
__global__ __launch_bounds__(256) void pack_weights(
    const float* __restrict__ w2, const float* __restrict__ w3,
    const float* __restrict__ w4, const float* __restrict__ w1,
    half_t* __restrict__ wp2, half_t* __restrict__ wp3, half_t* __restrict__ wp4,
    half_t* __restrict__ wp1)
{
  int t = blockIdx.x * 256 + threadIdx.x;
  if (t < 38400) {                       // conv2: [25][48][32]
    int tap = t / 1536, r = t % 1536, oc = r >> 5, c = r & 31;
    float v = (oc < 40 && c < 20) ? w2[(oc * 20 + c) * 25 + tap] : 0.f;
    wp2[t] = (half_t)v;
  } else if (t < 89600) {                // conv3: [25][32][64]
    int u = t - 38400;
    int tap = u / 2048, r = u % 2048, oc = r >> 6, c = r & 63;
    float v = (oc < 20 && c < 40) ? w3[(oc * 40 + c) * 25 + tap] : 0.f;
    wp3[u] = (half_t)v;
  } else if (t < 102400) {               // conv4: [25][16][32]
    int u = t - 89600;
    int tap = u / 512, r = u % 512, oc = r >> 5, c = r & 31;
    float v = (oc < 10 && c < 20) ? w4[(oc * 20 + c) * 25 + tap] : 0.f;
    wp4[u] = (half_t)v;
  } else if (t < 109568) {               // conv1: [7][32][32], k = kx*4+c
    int u = t - 102400;
    int ky = u / 1024, r = u % 1024, oc = r >> 5, k = r & 31;
    int kx = k >> 2, c = k & 3;
    float v = (oc < 20 && c < 3 && kx < 7) ? w1[((oc * 3 + c) * 7 + ky) * 7 + kx] : 0.f;
    wp1[u] = (half_t)v;
  }
}

// ---------------- conv1 (3->20, 7x7, pad 3) MFMA + relu + pool -> P1 f16 NHWC32 ----------------
// conv tile 16x32 px -> pooled 8x16; oc padded to 32 (2 M-tiles).
// A-tile rows padded 32->40 halves (2-way banks). B-tile is 8B/px (already fine).
__global__ __launch_bounds__(256) void conv1_mfma(
    const float* __restrict__ in, const half_t* __restrict__ wp,
    const float* __restrict__ bias, half_t* __restrict__ P1)
{
  __shared__ __align__(16) half_t ltile[22 * 40 * 4];   // 7040 B, row stride 40 px
  __shared__ __align__(16) half_t wlds[7 * 32 * 40];    // 17920 B, all taps, row stride 40
  const int b = blockIdx.z, ty0 = blockIdx.y * 16, tx0 = blockIdx.x * 32;
  const int tid = threadIdx.x;

  for (int i = tid; i < 896; i += 256) {                // 7 ky x 32 oc x 4 chunks
    int ky = i >> 7, r = i & 127, oc = r >> 2, part = r & 3;
    *(uint4*)(wlds + ky * 1280 + oc * 40 + part * 8) = *(const uint4*)(wp + i * 8);
  }

  const float* p0 = in + (size_t)b * 3 * IN_H * IN_W;
  for (int i = tid; i < 880; i += 256) {          // 22 rows x 40 cols (38 real + 2 zero)
    int r = i / 40, c = i - r * 40;
    int gy = ty0 - 3 + r, gx = tx0 - 3 + c;
    float v0 = 0.f, v1 = 0.f, v2 = 0.f;
    if (c < 38 && gy >= 0 && gy < IN_H && gx >= 0 && gx < IN_W) {
      size_t o = (size_t)gy * IN_W + gx;
      v0 = p0[o];
      v1 = p0[o + IN_H * IN_W];
      v2 = p0[o + 2 * IN_H * IN_W];
    }
    PK4 pk;
    pk.h[0] = (half_t)v0; pk.h[1] = (half_t)v1;
    pk.h[2] = (half_t)v2; pk.h[3] = (half_t)0.f;
    *(uint2*)(ltile + (r * 40 + c) * 4) = pk.u;
  }
  __syncthreads();

  const int wv = tid >> 6, ln = tid & 63, q = ln >> 4, nl = ln & 15;
  int baseB[8];
  #pragma unroll
  for (int j = 0; j < 8; ++j) {
    int g = j >> 2, ph = j & 3, phy = ph >> 1, phx = ph & 1;
    int ly = 2 * (wv * 2 + g) + phy;              // conv row 0..15
    int lx = 2 * nl + phx;                        // conv col 0..31
    baseB[j] = (ly * 40 + lx + 2 * q) * 4;        // halves; +ky*160 per K-step
  }
  const int aoff = nl * 40 + q * 8;
  floatx4 acc[2][8];
  #pragma unroll
  for (int mt = 0; mt < 2; ++mt)
    #pragma unroll
    for (int j = 0; j < 8; ++j) acc[mt][j] = (floatx4){0.f, 0.f, 0.f, 0.f};

  for (int ky = 0; ky < 7; ++ky) {
    const half_t* wb = wlds + ky * 1280;
    half8 A0 = *(const half8*)(wb + aoff);
    half8 A1 = *(const half8*)(wb + 640 + aoff);
    const half_t* tb = ltile + ky * 160;
    #pragma unroll
    for (int j = 0; j < 8; ++j) {
      U8 B;
      B.u[0] = *(const uint2*)(tb + baseB[j]);
      B.u[1] = *(const uint2*)(tb + baseB[j] + 4);
      acc[0][j] = __builtin_amdgcn_mfma_f32_16x16x32_f16(A0, B.v, acc[0][j], 0, 0, 0);
      acc[1][j] = __builtin_amdgcn_mfma_f32_16x16x32_f16(A1, B.v, acc[1][j], 0, 0, 0);
    }
  }

  floatx4 bv[2];
  #pragma unroll
  for (int mt = 0; mt < 2; ++mt)
    #pragma unroll
    for (int r = 0; r < 4; ++r) {
      int oc = mt * 16 + q * 4 + r;
      bv[mt][r] = (oc < 20) ? bias[oc] : 0.f;
    }
  const int pr0 = (ty0 >> 1) + wv * 2;
  const int pc = (tx0 >> 1) + nl;
  #pragma unroll
  for (int g = 0; g < 2; ++g) {
    size_t pxbase = (((size_t)b * P1H + pr0 + g) * P1W + pc) * 32;
    #pragma unroll
    for (int mt = 0; mt < 2; ++mt) {
      PK4 pk;
      #pragma unroll
      for (int r = 0; r < 4; ++r) {
        float x = fmaxf(fmaxf(acc[mt][g * 4 + 0][r], acc[mt][g * 4 + 1][r]),
                        fmaxf(acc[mt][g * 4 + 2][r], acc[mt][g * 4 + 3][r]));
        pk.h[r] = (half_t)fmaxf(x + bv[mt][r], 0.f);   // oc>=20: 0+0 -> 0 pad
      }
      *(uint2*)(P1 + pxbase + mt * 16 + q * 4) = pk.u;
    }
  }
}

// ---------------- conv2 (20->40, 5x5) MFMA + relu + pool -> P2 f16 NHWC64 ----------------
// lin pixel stride 32->40 halves: phase-mapped stride-2 lanes -> 4-way (was 16).
// wlds row stride 32->40: A-loads 2-way (was 8).
__global__ __launch_bounds__(256) void conv2_mfma(
    const half_t* __restrict__ P1, const half_t* __restrict__ wp,
    const float* __restrict__ bias, half_t* __restrict__ P2)
{
  __shared__ __align__(16) half_t lin[20 * 36 * 40];   // 57600 B
  __shared__ __align__(16) half_t wlds[2 * 48 * 40];   // 7680 B
  const int b = blockIdx.z, ty0 = blockIdx.y * 16, tx0 = blockIdx.x * 32;
  const int tid = threadIdx.x;
  for (int i = tid; i < 2880; i += 256) {
    int px = i >> 2, part = i & 3;
    int row = px / 36, col = px - row * 36;
    int gy = ty0 - 2 + row, gx = tx0 - 2 + col;
    uint4 v = make_uint4(0, 0, 0, 0);
    if (gy >= 0 && gy < P1H && gx >= 0 && gx < P1W)
      v = *(const uint4*)(P1 + (((size_t)b * P1H + gy) * P1W + gx) * 32 + part * 8);
    *(uint4*)(lin + px * 40 + part * 8) = v;
  }
  if (tid < 192) {
    int oc = tid >> 2, part = tid & 3;
    *(uint4*)(wlds + oc * 40 + part * 8) = *(const uint4*)(wp + tid * 8);
  }
  __syncthreads();

  const int wv = tid >> 6, ln = tid & 63, q = ln >> 4, nl = ln & 15;
  int baseB[8];
  #pragma unroll
  for (int j = 0; j < 8; ++j) {
    int g = j >> 2, ph = j & 3, phy = ph >> 1, phx = ph & 1;
    int ly = 2 * (wv * 2 + g) + phy;
    int lx = 2 * nl + phx;
    baseB[j] = (ly * 36 + lx) * 40 + q * 8;
  }
  const int aoff = nl * 40 + q * 8;
  floatx4 acc[3][8];
  #pragma unroll
  for (int mt = 0; mt < 3; ++mt)
    #pragma unroll
    for (int j = 0; j < 8; ++j) acc[mt][j] = (floatx4){0.f, 0.f, 0.f, 0.f};

  for (int tap = 0; tap < 25; ++tap) {
    const int bufc = tap & 1;
    uint4 wpre;
    const bool pre = (tap < 24) && (tid < 192);
    if (pre) wpre = *(const uint4*)(wp + (tap + 1) * 1536 + tid * 8);
    const int ky = tap / 5, kx = tap - (tap / 5) * 5;
    const int tapoff = (ky * 36 + kx) * 40;
    const half_t* wb = wlds + bufc * 1920;
    half8 A[3];
    #pragma unroll
    for (int mt = 0; mt < 3; ++mt)
      A[mt] = *(const half8*)(wb + mt * 640 + aoff);
    #pragma unroll
    for (int g = 0; g < 2; ++g) {
      half8 B[4];
      #pragma unroll
      for (int jj = 0; jj < 4; ++jj)
        B[jj] = *(const half8*)(lin + baseB[g * 4 + jj] + tapoff);
      #pragma unroll
      for (int mt = 0; mt < 3; ++mt)
        #pragma unroll
        for (int jj = 0; jj < 4; ++jj)
          acc[mt][g * 4 + jj] = __builtin_amdgcn_mfma_f32_16x16x32_f16(
              A[mt], B[jj], acc[mt][g * 4 + jj], 0, 0, 0);
    }
    if (pre) {
      int oc = tid >> 2, part = tid & 3;
      *(uint4*)(wlds + (1 - bufc) * 1920 + oc * 40 + part * 8) = wpre;
    }
    __syncthreads();
  }

  floatx4 bv[3];
  #pragma unroll
  for (int mt = 0; mt < 3; ++mt)
    #pragma unroll
    for (int r = 0; r < 4; ++r) {
      int oc = mt * 16 + q * 4 + r;
      bv[mt][r] = (oc < 40) ? bias[oc] : 0.f;
    }
  const int pr0 = (ty0 >> 1) + wv * 2;
  const int pc = (tx0 >> 1) + nl;
  #pragma unroll
  for (int g = 0; g < 2; ++g) {
    size_t pxbase = (((size_t)b * P2H + pr0 + g) * P2W + pc) * 64;
    #pragma unroll
    for (int mt = 0; mt < 3; ++mt) {
      PK4 pk;
      #pragma unroll
      for (int r = 0; r < 4; ++r) {
        float x = fmaxf(fmaxf(acc[mt][g * 4 + 0][r], acc[mt][g * 4 + 1][r]),
                        fmaxf(acc[mt][g * 4 + 2][r], acc[mt][g * 4 + 3][r]));
        pk.h[r] = (half_t)fmaxf(x + bv[mt][r], 0.f);
      }
      *(uint2*)(P2 + pxbase + mt * 16 + q * 4) = pk.u;
    }
    if (q < 2)
      *(uint4*)(P2 + pxbase + 48 + q * 8) = make_uint4(0, 0, 0, 0);  // oc 48..63 = 0
  }
}

// ---------------- conv3 (40->20, 5x5) MFMA + relu -> X3 f16 NHWC32 ----------------
// lin pixel stride 64->72 halves: stride-1 lanes -> 2-way (was 16).
// wlds row stride 64->72: A-loads 2-way (was 16).
__global__ __launch_bounds__(256) void conv3_mfma(
    const half_t* __restrict__ P2, const half_t* __restrict__ wp,
    const float* __restrict__ bias, half_t* __restrict__ X3)
{
  __shared__ __align__(16) half_t lin[12 * 36 * 72];   // 62208 B
  __shared__ __align__(16) half_t wlds[2 * 32 * 72];   // 9216 B
  const int b = blockIdx.z, ty0 = blockIdx.y * 8, tx0 = blockIdx.x * 32;
  const int tid = threadIdx.x;
  for (int i = tid; i < 3456; i += 256) {
    int px = i >> 3, part = i & 7;
    int row = px / 36, col = px - row * 36;
    int gy = ty0 - 2 + row, gx = tx0 - 2 + col;
    uint4 v = make_uint4(0, 0, 0, 0);
    if (gy >= 0 && gy < P2H && gx >= 0 && gx < P2W)
      v = *(const uint4*)(P2 + (((size_t)b * P2H + gy) * P2W + gx) * 64 + part * 8);
    *(uint4*)(lin + px * 72 + part * 8) = v;
  }
  {
    int oc = tid >> 3, part = tid & 7;
    *(uint4*)(wlds + oc * 72 + part * 8) = *(const uint4*)(wp + tid * 8);
  }
  __syncthreads();

  const int wv = tid >> 6, ln = tid & 63, q = ln >> 4, nl = ln & 15;
  int baseB[4];
  #pragma unroll
  for (int j = 0; j < 4; ++j) {
    int nt = wv * 4 + j;
    int ly = nt >> 1, lx = (nt & 1) * 16 + nl;
    baseB[j] = (ly * 36 + lx) * 72 + q * 8;
  }
  const int aoff = nl * 72 + q * 8;
  floatx4 acc[2][4];
  #pragma unroll
  for (int mt = 0; mt < 2; ++mt)
    #pragma unroll
    for (int j = 0; j < 4; ++j) acc[mt][j] = (floatx4){0.f, 0.f, 0.f, 0.f};

  for (int tap = 0; tap < 25; ++tap) {
    const int bufc = tap & 1;
    uint4 wpre;
    const bool pre = (tap < 24);
    if (pre) wpre = *(const uint4*)(wp + (tap + 1) * 2048 + tid * 8);
    const int ky = tap / 5, kx = tap - (tap / 5) * 5;
    const half_t* wb = wlds + bufc * 2304;
    #pragma unroll
    for (int cb = 0; cb < 2; ++cb) {
      const int tapoff = (ky * 36 + kx) * 72 + cb * 32;
      half8 A[2];
      #pragma unroll
      for (int mt = 0; mt < 2; ++mt)
        A[mt] = *(const half8*)(wb + mt * 1152 + cb * 32 + aoff);
      half8 B[4];
      #pragma unroll
      for (int jj = 0; jj < 4; ++jj)
        B[jj] = *(const half8*)(lin + baseB[jj] + tapoff);
      #pragma unroll
      for (int mt = 0; mt < 2; ++mt)
        #pragma unroll
        for (int jj = 0; jj < 4; ++jj)
          acc[mt][jj] = __builtin_amdgcn_mfma_f32_16x16x32_f16(
              A[mt], B[jj], acc[mt][jj], 0, 0, 0);
    }
    if (pre) {
      int oc = tid >> 3, part = tid & 7;
      *(uint4*)(wlds + (1 - bufc) * 2304 + oc * 72 + part * 8) = wpre;
    }
    __syncthreads();
  }

  floatx4 bv[2];
  #pragma unroll
  for (int mt = 0; mt < 2; ++mt)
    #pragma unroll
    for (int r = 0; r < 4; ++r) {
      int oc = mt * 16 + q * 4 + r;
      bv[mt][r] = (oc < 20) ? bias[oc] : 0.f;
    }
  #pragma unroll
  for (int j = 0; j < 4; ++j) {
    int nt = wv * 4 + j;
    int y = ty0 + (nt >> 1), x = tx0 + (nt & 1) * 16 + nl;
    size_t pxbase = (((size_t)b * P2H + y) * P2W + x) * 32;
    #pragma unroll
    for (int mt = 0; mt < 2; ++mt) {
      floatx4 v = acc[mt][j];
      PK4 pk;
      #pragma unroll
      for (int r = 0; r < 4; ++r) pk.h[r] = (half_t)fmaxf(v[r] + bv[mt][r], 0.f);
      *(uint2*)(X3 + pxbase + mt * 16 + q * 4) = pk.u;
    }
  }
}

// ---------------- conv4 (20->10, 5x5) MFMA + relu -> X4 fp32 NHWC10 ----------------
// lin pixel stride 32->40 halves: stride-1 lanes -> 2-way (was 8). wlds stride 40.
__global__ __launch_bounds__(256) void conv4_mfma(
    const half_t* __restrict__ X3, const half_t* __restrict__ wp,
    const float* __restrict__ bias, float* __restrict__ X4)
{
  __shared__ __align__(16) half_t lin[20 * 36 * 40];   // 57600 B
  __shared__ __align__(16) half_t wlds[2 * 16 * 40];   // 2560 B
  const int b = blockIdx.z, ty0 = blockIdx.y * 16, tx0 = blockIdx.x * 32;
  const int tid = threadIdx.x;
  for (int i = tid; i < 2880; i += 256) {
    int px = i >> 2, part = i & 3;
    int row = px / 36, col = px - row * 36;
    int gy = ty0 - 2 + row, gx = tx0 - 2 + col;
    uint4 v = make_uint4(0, 0, 0, 0);
    if (gy >= 0 && gy < P2H && gx >= 0 && gx < P2W)
      v = *(const uint4*)(X3 + (((size_t)b * P2H + gy) * P2W + gx) * 32 + part * 8);
    *(uint4*)(lin + px * 40 + part * 8) = v;
  }
  if (tid < 64) {
    int oc = tid >> 2, part = tid & 3;
    *(uint4*)(wlds + oc * 40 + part * 8) = *(const uint4*)(wp + tid * 8);
  }
  __syncthreads();

  const int wv = tid >> 6, ln = tid & 63, q = ln >> 4, nl = ln & 15;
  int baseB[8];
  #pragma unroll
  for (int j = 0; j < 8; ++j) {
    int nt = wv * 8 + j;
    int ly = nt >> 1, lx = (nt & 1) * 16 + nl;
    baseB[j] = (ly * 36 + lx) * 40 + q * 8;
  }
  const int aoff = nl * 40 + q * 8;
  floatx4 acc[8];
  #pragma unroll
  for (int j = 0; j < 8; ++j) acc[j] = (floatx4){0.f, 0.f, 0.f, 0.f};

  for (int tap = 0; tap < 25; ++tap) {
    const int bufc = tap & 1;
    uint4 wpre;
    const bool pre = (tap < 24) && (tid < 64);
    if (pre) wpre = *(const uint4*)(wp + (tap + 1) * 512 + tid * 8);
    const int ky = tap / 5, kx = tap - (tap / 5) * 5;
    const int tapoff = (ky * 36 + kx) * 40;
    const half_t* wb = wlds + bufc * 640;
    half8 A = *(const half8*)(wb + aoff);
    #pragma unroll
    for (int j = 0; j < 8; ++j) {
      half8 B = *(const half8*)(lin + baseB[j] + tapoff);
      acc[j] = __builtin_amdgcn_mfma_f32_16x16x32_f16(A, B, acc[j], 0, 0, 0);
    }
    if (pre) {
      int oc = tid >> 2, part = tid & 3;
      *(uint4*)(wlds + (1 - bufc) * 640 + oc * 40 + part * 8) = wpre;
    }
    __syncthreads();
  }

  float bv[4];
  #pragma unroll
  for (int r = 0; r < 4; ++r) {
    int oc = q * 4 + r;
    bv[r] = (oc < 10) ? bias[oc] : 0.f;
  }
  #pragma unroll
  for (int j = 0; j < 8; ++j) {
    int nt = wv * 8 + j;
    int y = ty0 + (nt >> 1), x = tx0 + (nt & 1) * 16 + nl;
    float* dst = X4 + (((size_t)b * P2H + y) * P2W + x) * 10;
    floatx4 v = acc[j];
    float r0 = fmaxf(v[0] + bv[0], 0.f), r1 = fmaxf(v[1] + bv[1], 0.f);
    float r2 = fmaxf(v[2] + bv[2], 0.f), r3 = fmaxf(v[3] + bv[3], 0.f);
    if (q < 2) {
      *(float2*)(dst + q * 4)     = make_float2(r0, r1);
      *(float2*)(dst + q * 4 + 2) = make_float2(r2, r3);
    } else if (q == 2) {
      *(float2*)(dst + 8) = make_float2(r0, r1);   // oc 8,9
    }
  }
}

// ---------------- conv5 (10->1, 1x1) + gray residual + relu ----------------
__global__ __launch_bounds__(256) void conv5_res(
    const float* __restrict__ X4, const float* __restrict__ w5,
    const float* __restrict__ b5, const float* __restrict__ in,
    float* __restrict__ out)
{
  const int idx = blockIdx.x * 256 + threadIdx.x;  // 0 .. 8*192*256-1
  const int j = idx & 255;
  const int bi = idx >> 8;
  const int i = bi % 192;
  const int b = bi / 192;
  const float* xp = X4 + (((size_t)b * P2H + i) * P2W + j) * 10;
  float sum = b5[0];
  #pragma unroll
  for (int c = 0; c < 10; ++c) sum += w5[c] * xp[c];
  const int r0 = 4 * i + 1, c0 = 4 * j + 1;
  float g = 0.f;
  #pragma unroll
  for (int ch = 0; ch < 3; ++ch) {
    const float coef = (ch == 0) ? 0.299f : ((ch == 1) ? 0.587f : 0.114f);
    const float* q = in + ((size_t)b * 3 + ch) * IN_H * IN_W;
    g += coef * (q[(size_t)r0 * IN_W + c0] + q[(size_t)r0 * IN_W + c0 + 1] +
                 q[(size_t)(r0 + 1) * IN_W + c0] + q[(size_t)(r0 + 1) * IN_W + c0 + 1]);
  }
  g *= 0.25f;
  out[idx] = fmaxf(sum + fmaxf(g, 0.f), 0.f);
}

extern "C" void kernel_launch(void* const* d_in, const int* in_sizes, int n_in,
                              void* d_out, int out_size, void* d_ws, size_t ws_size,
                              hipStream_t stream) {
  const float* input = (const float*)d_in[0];
  const float* w1 = (const float*)d_in[1];  const float* b1 = (const float*)d_in[2];
  const float* w2 = (const float*)d_in[3];  const float* b2 = (const float*)d_in[4];
  const float* w3 = (const float*)d_in[5];  const float* b3 = (const float*)d_in[6];
  const float* w4 = (const float*)d_in[7];  const float* b4 = (const float*)d_in[8];
  const float* w5 = (const float*)d_in[9];  const float* b5 = (const float*)d_in[10];
  float* out = (float*)d_out;
  char* ws = (char*)d_ws;

  half_t* P2h = (half_t*)(ws + OFF_P2);
  half_t* P1h = (half_t*)(ws + OFF_P1);
  half_t* X3h = (half_t*)(ws + OFF_X3);
  float*  X4f = (float*)(ws + OFF_X4);
  half_t* wp2 = (half_t*)(ws + OFF_W2);
  half_t* wp3 = (half_t*)(ws + OFF_W3);
  half_t* wp4 = (half_t*)(ws + OFF_W4);
  half_t* wp1 = (half_t*)(ws + OFF_W1);

  pack_weights<<<432, 256, 0, stream>>>(w2, w3, w4, w1, wp2, wp3, wp4, wp1);
  conv1_mfma<<<dim3(32, 48, 8), 256, 0, stream>>>(input, wp1, b1, P1h);
  conv2_mfma<<<dim3(16, 24, 8), 256, 0, stream>>>(P1h, wp2, b2, P2h);
  conv3_mfma<<<dim3(8, 24, 8), 256, 0, stream>>>(P2h, wp3, b3, X3h);
  conv4_mfma<<<dim3(8, 12, 8), 256, 0, stream>>>(X3h, wp4, b4, X4f);
  conv5_res<<<1536, 256, 0, stream>>>(X4f, w5, b5, input, out);
}

// Round 6
// 468.578 us; speedup vs baseline: 1.1835x; 1.0242x over previous
//
#include <hip/hip_runtime.h>

// Res_MCNN_branch2 on gfx950 — all convs via f16 MFMA implicit-GEMM (16x16x32).
// R6: conv2/3/4 K-loops are BARRIER-FREE — weights read per-tap straight from
// global (L1/L2-resident, coalesced 16B/lane), tap loop fully unrolled so LDS
// offsets are immediates and the compiler software-pipelines loads across taps.
// conv2/conv4 use 8x32 conv tiles (lin 34.6 KB -> 4 blocks/CU).
// LDS bank rule: pixel records padded to 40/72 halves (16B-mult, not 128B-mult).
// conv1: K = kx*4+c, 7 barrier-free K-steps, phase-pooled -> P1 NHWC32.
// conv2: 25 taps x 32c, phase-pooled -> P2 NHWC64. conv3: 25x64 -> X3 NHWC32.
// conv4: 25x32 -> X4 fp32 NHWC10. conv5: 1x1 + gray residual (4x bilinear ==
// 2x2 avg at rows/cols {4i+1,4i+2}).

typedef _Float16 half_t;
typedef _Float16 half8 __attribute__((ext_vector_type(8)));
typedef float floatx4 __attribute__((ext_vector_type(4)));

#define IN_H 768
#define IN_W 1024
#define P1H 384
#define P1W 512
#define P2H 192
#define P2W 256

// workspace offsets (bytes)
#define OFF_P2 0ULL                 // f16 [8][192][256][64]  = 50,331,648
#define OFF_P1 50331648ULL          // f16 [8][384][512][32]  = 100,663,296
#define OFF_X3 50331648ULL          // reuse P1 region after conv2
#define OFF_X4 0ULL                 // fp32 [8][192][256][10] reuse P2 region after conv3
#define OFF_W2 150994944ULL         // f16 [25][48][32] = 76,800 el
#define OFF_W3 151072768ULL         // f16 [25][32][64] = 102,400 el
#define OFF_W4 151175168ULL         // f16 [25][16][32] = 25,600 el
#define OFF_W1 151226368ULL         // f16 [7][32][32]  = 7,168 el

union PK4 { half_t h[4]; uint2 u; };
union U8 { half8 v; uint2 u[2]; };

// ---------------- weight pre-pack (fp32 OIHW -> f16 packed, linear) ----------------
__global__ __launch_bounds__(256) void pack_weights(
    const float* __restrict__ w2, const float* __restrict__ w3,
    const float* __restrict__ w4, const float* __restrict__ w1,
    half_t* __restrict__ wp2, half_t* __restrict__ wp3, half_t* __restrict__ wp4,
    half_t* __restrict__ wp1)
{
  int t = blockIdx.x * 256 + threadIdx.x;
  if (t < 38400) {                       // conv2: [25][48][32]
    int tap = t / 1536, r = t % 1536, oc = r >> 5, c = r & 31;
    float v = (oc < 40 && c < 20) ? w2[(oc * 20 + c) * 25 + tap] : 0.f;
    wp2[t] = (half_t)v;
  } else if (t < 89600) {                // conv3: [25][32][64]
    int u = t - 38400;
    int tap = u / 2048, r = u % 2048, oc = r >> 6, c = r & 63;
    float v = (oc < 20 && c < 40) ? w3[(oc * 40 + c) * 25 + tap] : 0.f;
    wp3[u] = (half_t)v;
  } else if (t < 102400) {               // conv4: [25][16][32]
    int u = t - 89600;
    int tap = u / 512, r = u % 512, oc = r >> 5, c = r & 31;
    float v = (oc < 10 && c < 20) ? w4[(oc * 20 + c) * 25 + tap] : 0.f;
    wp4[u] = (half_t)v;
  } else if (t < 109568) {               // conv1: [7][32][32], k = kx*4+c
    int u = t - 102400;
    int ky = u / 1024, r = u % 1024, oc = r >> 5, k = r & 31;
    int kx = k >> 2, c = k & 3;
    float v = (oc < 20 && c < 3 && kx < 7) ? w1[((oc * 3 + c) * 7 + ky) * 7 + kx] : 0.f;
    wp1[u] = (half_t)v;
  }
}

// ---------------- conv1 (3->20, 7x7, pad 3) MFMA + relu + pool -> P1 f16 NHWC32 ----------------
// (unchanged from R5)
__global__ __launch_bounds__(256) void conv1_mfma(
    const float* __restrict__ in, const half_t* __restrict__ wp,
    const float* __restrict__ bias, half_t* __restrict__ P1)
{
  __shared__ __align__(16) half_t ltile[22 * 40 * 4];   // 7040 B, row stride 40 px
  __shared__ __align__(16) half_t wlds[7 * 32 * 40];    // 17920 B, all taps, row stride 40
  const int b = blockIdx.z, ty0 = blockIdx.y * 16, tx0 = blockIdx.x * 32;
  const int tid = threadIdx.x;

  for (int i = tid; i < 896; i += 256) {                // 7 ky x 32 oc x 4 chunks
    int ky = i >> 7, r = i & 127, oc = r >> 2, part = r & 3;
    *(uint4*)(wlds + ky * 1280 + oc * 40 + part * 8) = *(const uint4*)(wp + i * 8);
  }

  const float* p0 = in + (size_t)b * 3 * IN_H * IN_W;
  for (int i = tid; i < 880; i += 256) {          // 22 rows x 40 cols (38 real + 2 zero)
    int r = i / 40, c = i - r * 40;
    int gy = ty0 - 3 + r, gx = tx0 - 3 + c;
    float v0 = 0.f, v1 = 0.f, v2 = 0.f;
    if (c < 38 && gy >= 0 && gy < IN_H && gx >= 0 && gx < IN_W) {
      size_t o = (size_t)gy * IN_W + gx;
      v0 = p0[o];
      v1 = p0[o + IN_H * IN_W];
      v2 = p0[o + 2 * IN_H * IN_W];
    }
    PK4 pk;
    pk.h[0] = (half_t)v0; pk.h[1] = (half_t)v1;
    pk.h[2] = (half_t)v2; pk.h[3] = (half_t)0.f;
    *(uint2*)(ltile + (r * 40 + c) * 4) = pk.u;
  }
  __syncthreads();

  const int wv = tid >> 6, ln = tid & 63, q = ln >> 4, nl = ln & 15;
  int baseB[8];
  #pragma unroll
  for (int j = 0; j < 8; ++j) {
    int g = j >> 2, ph = j & 3, phy = ph >> 1, phx = ph & 1;
    int ly = 2 * (wv * 2 + g) + phy;              // conv row 0..15
    int lx = 2 * nl + phx;                        // conv col 0..31
    baseB[j] = (ly * 40 + lx + 2 * q) * 4;        // halves; +ky*160 per K-step
  }
  const int aoff = nl * 40 + q * 8;
  floatx4 acc[2][8];
  #pragma unroll
  for (int mt = 0; mt < 2; ++mt)
    #pragma unroll
    for (int j = 0; j < 8; ++j) acc[mt][j] = (floatx4){0.f, 0.f, 0.f, 0.f};

  #pragma unroll
  for (int ky = 0; ky < 7; ++ky) {
    const half_t* wb = wlds + ky * 1280;
    half8 A0 = *(const half8*)(wb + aoff);
    half8 A1 = *(const half8*)(wb + 640 + aoff);
    const half_t* tb = ltile + ky * 160;
    #pragma unroll
    for (int j = 0; j < 8; ++j) {
      U8 B;
      B.u[0] = *(const uint2*)(tb + baseB[j]);
      B.u[1] = *(const uint2*)(tb + baseB[j] + 4);
      acc[0][j] = __builtin_amdgcn_mfma_f32_16x16x32_f16(A0, B.v, acc[0][j], 0, 0, 0);
      acc[1][j] = __builtin_amdgcn_mfma_f32_16x16x32_f16(A1, B.v, acc[1][j], 0, 0, 0);
    }
  }

  floatx4 bv[2];
  #pragma unroll
  for (int mt = 0; mt < 2; ++mt)
    #pragma unroll
    for (int r = 0; r < 4; ++r) {
      int oc = mt * 16 + q * 4 + r;
      bv[mt][r] = (oc < 20) ? bias[oc] : 0.f;
    }
  const int pr0 = (ty0 >> 1) + wv * 2;
  const int pc = (tx0 >> 1) + nl;
  #pragma unroll
  for (int g = 0; g < 2; ++g) {
    size_t pxbase = (((size_t)b * P1H + pr0 + g) * P1W + pc) * 32;
    #pragma unroll
    for (int mt = 0; mt < 2; ++mt) {
      PK4 pk;
      #pragma unroll
      for (int r = 0; r < 4; ++r) {
        float x = fmaxf(fmaxf(acc[mt][g * 4 + 0][r], acc[mt][g * 4 + 1][r]),
                        fmaxf(acc[mt][g * 4 + 2][r], acc[mt][g * 4 + 3][r]));
        pk.h[r] = (half_t)fmaxf(x + bv[mt][r], 0.f);   // oc>=20: 0+0 -> 0 pad
      }
      *(uint2*)(P1 + pxbase + mt * 16 + q * 4) = pk.u;
    }
  }
}

// ---------------- conv2 (20->40, 5x5) MFMA + relu + pool -> P2 f16 NHWC64 ----------------
// conv tile 8x32 -> pooled 4x16; lin 34.6 KB -> 4 blocks/CU. No weight LDS:
// A-fragments per tap from global (coalesced, cached). Barrier-free unrolled K-loop.
__global__ __launch_bounds__(256) void conv2_mfma(
    const half_t* __restrict__ P1, const half_t* __restrict__ wp,
    const float* __restrict__ bias, half_t* __restrict__ P2)
{
  __shared__ __align__(16) half_t lin[12 * 36 * 40];   // 34560 B
  const int b = blockIdx.z, ty0 = blockIdx.y * 8, tx0 = blockIdx.x * 32;
  const int tid = threadIdx.x;
  for (int i = tid; i < 1728; i += 256) {              // 432 px x 4 parts
    int px = i >> 2, part = i & 3;
    int row = px / 36, col = px - row * 36;
    int gy = ty0 - 2 + row, gx = tx0 - 2 + col;
    uint4 v = make_uint4(0, 0, 0, 0);
    if (gy >= 0 && gy < P1H && gx >= 0 && gx < P1W)
      v = *(const uint4*)(P1 + (((size_t)b * P1H + gy) * P1W + gx) * 32 + part * 8);
    *(uint4*)(lin + px * 40 + part * 8) = v;
  }
  __syncthreads();

  const int wv = tid >> 6, ln = tid & 63, q = ln >> 4, nl = ln & 15;
  int baseB[4];
  #pragma unroll
  for (int j = 0; j < 4; ++j) {                        // j = phy*2+phx
    int phy = j >> 1, phx = j & 1;
    int ly = 2 * wv + phy;                             // conv row 0..7
    int lx = 2 * nl + phx;                             // conv col 0..31
    baseB[j] = (ly * 36 + lx) * 40 + q * 8;
  }
  const half_t* wA = wp + nl * 32 + q * 8;             // + tap*1536 + mt*512
  floatx4 acc[3][4];
  #pragma unroll
  for (int mt = 0; mt < 3; ++mt)
    #pragma unroll
    for (int j = 0; j < 4; ++j) acc[mt][j] = (floatx4){0.f, 0.f, 0.f, 0.f};

  #pragma unroll
  for (int tap = 0; tap < 25; ++tap) {
    const int ky = tap / 5, kx = tap - (tap / 5) * 5;  // compile-time (unrolled)
    const int tapoff = (ky * 36 + kx) * 40;
    half8 A[3];
    #pragma unroll
    for (int mt = 0; mt < 3; ++mt)
      A[mt] = *(const half8*)(wA + tap * 1536 + mt * 512);
    half8 B[4];
    #pragma unroll
    for (int j = 0; j < 4; ++j)
      B[j] = *(const half8*)(lin + baseB[j] + tapoff);
    #pragma unroll
    for (int mt = 0; mt < 3; ++mt)
      #pragma unroll
      for (int j = 0; j < 4; ++j)
        acc[mt][j] = __builtin_amdgcn_mfma_f32_16x16x32_f16(A[mt], B[j], acc[mt][j], 0, 0, 0);
  }

  floatx4 bv[3];
  #pragma unroll
  for (int mt = 0; mt < 3; ++mt)
    #pragma unroll
    for (int r = 0; r < 4; ++r) {
      int oc = mt * 16 + q * 4 + r;
      bv[mt][r] = (oc < 40) ? bias[oc] : 0.f;
    }
  const int pr = (ty0 >> 1) + wv;
  const int pc = (tx0 >> 1) + nl;
  size_t pxbase = (((size_t)b * P2H + pr) * P2W + pc) * 64;
  #pragma unroll
  for (int mt = 0; mt < 3; ++mt) {
    PK4 pk;
    #pragma unroll
    for (int r = 0; r < 4; ++r) {
      float x = fmaxf(fmaxf(acc[mt][0][r], acc[mt][1][r]),
                      fmaxf(acc[mt][2][r], acc[mt][3][r]));
      pk.h[r] = (half_t)fmaxf(x + bv[mt][r], 0.f);
    }
    *(uint2*)(P2 + pxbase + mt * 16 + q * 4) = pk.u;
  }
  if (q < 2)
    *(uint4*)(P2 + pxbase + 48 + q * 8) = make_uint4(0, 0, 0, 0);  // oc 48..63 = 0
}

// ---------------- conv3 (40->20, 5x5) MFMA + relu -> X3 f16 NHWC32 ----------------
// No weight LDS; barrier-free unrolled K-loop (25 taps x 2 c-blocks).
__global__ __launch_bounds__(256) void conv3_mfma(
    const half_t* __restrict__ P2, const half_t* __restrict__ wp,
    const float* __restrict__ bias, half_t* __restrict__ X3)
{
  __shared__ __align__(16) half_t lin[12 * 36 * 72];   // 62208 B
  const int b = blockIdx.z, ty0 = blockIdx.y * 8, tx0 = blockIdx.x * 32;
  const int tid = threadIdx.x;
  for (int i = tid; i < 3456; i += 256) {
    int px = i >> 3, part = i & 7;
    int row = px / 36, col = px - row * 36;
    int gy = ty0 - 2 + row, gx = tx0 - 2 + col;
    uint4 v = make_uint4(0, 0, 0, 0);
    if (gy >= 0 && gy < P2H && gx >= 0 && gx < P2W)
      v = *(const uint4*)(P2 + (((size_t)b * P2H + gy) * P2W + gx) * 64 + part * 8);
    *(uint4*)(lin + px * 72 + part * 8) = v;
  }
  __syncthreads();

  const int wv = tid >> 6, ln = tid & 63, q = ln >> 4, nl = ln & 15;
  int baseB[4];
  #pragma unroll
  for (int j = 0; j < 4; ++j) {
    int nt = wv * 4 + j;
    int ly = nt >> 1, lx = (nt & 1) * 16 + nl;
    baseB[j] = (ly * 36 + lx) * 72 + q * 8;
  }
  const half_t* wA = wp + nl * 64 + q * 8;             // + tap*2048 + mt*1024 + cb*32
  floatx4 acc[2][4];
  #pragma unroll
  for (int mt = 0; mt < 2; ++mt)
    #pragma unroll
    for (int j = 0; j < 4; ++j) acc[mt][j] = (floatx4){0.f, 0.f, 0.f, 0.f};

  #pragma unroll
  for (int tap = 0; tap < 25; ++tap) {
    const int ky = tap / 5, kx = tap - (tap / 5) * 5;
    #pragma unroll
    for (int cb = 0; cb < 2; ++cb) {
      const int tapoff = (ky * 36 + kx) * 72 + cb * 32;
      half8 A[2];
      #pragma unroll
      for (int mt = 0; mt < 2; ++mt)
        A[mt] = *(const half8*)(wA + tap * 2048 + mt * 1024 + cb * 32);
      half8 B[4];
      #pragma unroll
      for (int jj = 0; jj < 4; ++jj)
        B[jj] = *(const half8*)(lin + baseB[jj] + tapoff);
      #pragma unroll
      for (int mt = 0; mt < 2; ++mt)
        #pragma unroll
        for (int jj = 0; jj < 4; ++jj)
          acc[mt][jj] = __builtin_amdgcn_mfma_f32_16x16x32_f16(
              A[mt], B[jj], acc[mt][jj], 0, 0, 0);
    }
  }

  floatx4 bv[2];
  #pragma unroll
  for (int mt = 0; mt < 2; ++mt)
    #pragma unroll
    for (int r = 0; r < 4; ++r) {
      int oc = mt * 16 + q * 4 + r;
      bv[mt][r] = (oc < 20) ? bias[oc] : 0.f;
    }
  #pragma unroll
  for (int j = 0; j < 4; ++j) {
    int nt = wv * 4 + j;
    int y = ty0 + (nt >> 1), x = tx0 + (nt & 1) * 16 + nl;
    size_t pxbase = (((size_t)b * P2H + y) * P2W + x) * 32;
    #pragma unroll
    for (int mt = 0; mt < 2; ++mt) {
      floatx4 v = acc[mt][j];
      PK4 pk;
      #pragma unroll
      for (int r = 0; r < 4; ++r) pk.h[r] = (half_t)fmaxf(v[r] + bv[mt][r], 0.f);
      *(uint2*)(X3 + pxbase + mt * 16 + q * 4) = pk.u;
    }
  }
}

// ---------------- conv4 (20->10, 5x5) MFMA + relu -> X4 fp32 NHWC10 ----------------
// conv tile 8x32; lin 34.6 KB -> 4 blocks/CU. No weight LDS; barrier-free unrolled.
__global__ __launch_bounds__(256) void conv4_mfma(
    const half_t* __restrict__ X3, const half_t* __restrict__ wp,
    const float* __restrict__ bias, float* __restrict__ X4)
{
  __shared__ __align__(16) half_t lin[12 * 36 * 40];   // 34560 B
  const int b = blockIdx.z, ty0 = blockIdx.y * 8, tx0 = blockIdx.x * 32;
  const int tid = threadIdx.x;
  for (int i = tid; i < 1728; i += 256) {
    int px = i >> 2, part = i & 3;
    int row = px / 36, col = px - row * 36;
    int gy = ty0 - 2 + row, gx = tx0 - 2 + col;
    uint4 v = make_uint4(0, 0, 0, 0);
    if (gy >= 0 && gy < P2H && gx >= 0 && gx < P2W)
      v = *(const uint4*)(X3 + (((size_t)b * P2H + gy) * P2W + gx) * 32 + part * 8);
    *(uint4*)(lin + px * 40 + part * 8) = v;
  }
  __syncthreads();

  const int wv = tid >> 6, ln = tid & 63, q = ln >> 4, nl = ln & 15;
  int baseB[4];
  #pragma unroll
  for (int j = 0; j < 4; ++j) {
    int nt = wv * 4 + j;
    int ly = nt >> 1, lx = (nt & 1) * 16 + nl;
    baseB[j] = (ly * 36 + lx) * 40 + q * 8;
  }
  const half_t* wA = wp + nl * 32 + q * 8;             // + tap*512
  floatx4 acc[4];
  #pragma unroll
  for (int j = 0; j < 4; ++j) acc[j] = (floatx4){0.f, 0.f, 0.f, 0.f};

  #pragma unroll
  for (int tap = 0; tap < 25; ++tap) {
    const int ky = tap / 5, kx = tap - (tap / 5) * 5;
    const int tapoff = (ky * 36 + kx) * 40;
    half8 A = *(const half8*)(wA + tap * 512);
    #pragma unroll
    for (int j = 0; j < 4; ++j) {
      half8 B = *(const half8*)(lin + baseB[j] + tapoff);
      acc[j] = __builtin_amdgcn_mfma_f32_16x16x32_f16(A, B, acc[j], 0, 0, 0);
    }
  }

  float bv[4];
  #pragma unroll
  for (int r = 0; r < 4; ++r) {
    int oc = q * 4 + r;
    bv[r] = (oc < 10) ? bias[oc] : 0.f;
  }
  #pragma unroll
  for (int j = 0; j < 4; ++j) {
    int nt = wv * 4 + j;
    int y = ty0 + (nt >> 1), x = tx0 + (nt & 1) * 16 + nl;
    float* dst = X4 + (((size_t)b * P2H + y) * P2W + x) * 10;
    floatx4 v = acc[j];
    float r0 = fmaxf(v[0] + bv[0], 0.f), r1 = fmaxf(v[1] + bv[1], 0.f);
    float r2 = fmaxf(v[2] + bv[2], 0.f), r3 = fmaxf(v[3] + bv[3], 0.f);
    if (q < 2) {
      *(float2*)(dst + q * 4)     = make_float2(r0, r1);
      *(float2*)(dst + q * 4 + 2) = make_float2(r2, r3);
    } else if (q == 2) {
      *(float2*)(dst + 8) = make_float2(r0, r1);   // oc 8,9
    }
  }
}

// ---------------- conv5 (10->1, 1x1) + gray residual + relu ----------------
__global__ __launch_bounds__(256) void conv5_res(
    const float* __restrict__ X4, const float* __restrict__ w5,
    const float* __restrict__ b5, const float* __restrict__ in,
    float* __restrict__ out)
{
  const int idx = blockIdx.x * 256 + threadIdx.x;  // 0 .. 8*192*256-1
  const int j = idx & 255;
  const int bi = idx >> 8;
  const int i = bi % 192;
  const int b = bi / 192;
  const float* xp = X4 + (((size_t)b * P2H + i) * P2W + j) * 10;
  float sum = b5[0];
  #pragma unroll
  for (int c = 0; c < 10; ++c) sum += w5[c] * xp[c];
  const int r0 = 4 * i + 1, c0 = 4 * j + 1;
  float g = 0.f;
  #pragma unroll
  for (int ch = 0; ch < 3; ++ch) {
    const float coef = (ch == 0) ? 0.299f : ((ch == 1) ? 0.587f : 0.114f);
    const float* q = in + ((size_t)b * 3 + ch) * IN_H * IN_W;
    g += coef * (q[(size_t)r0 * IN_W + c0] + q[(size_t)r0 * IN_W + c0 + 1] +
                 q[(size_t)(r0 + 1) * IN_W + c0] + q[(size_t)(r0 + 1) * IN_W + c0 + 1]);
  }
  g *= 0.25f;
  out[idx] = fmaxf(sum + fmaxf(g, 0.f), 0.f);
}

extern "C" void kernel_launch(void* const* d_in, const int* in_sizes, int n_in,
                              void* d_out, int out_size, void* d_ws, size_t ws_size,
                              hipStream_t stream) {
  const float* input = (const float*)d_in[0];
  const float* w1 = (const float*)d_in[1];  const float* b1 = (const float*)d_in[2];
  const float* w2 = (const float*)d_in[3];  const float* b2 = (const float*)d_in[4];
  const float* w3 = (const float*)d_in[5];  const float* b3 = (const float*)d_in[6];
  const float* w4 = (const float*)d_in[7];  const float* b4 = (const float*)d_in[8];
  const float* w5 = (const float*)d_in[9];  const float* b5 = (const float*)d_in[10];
  float* out = (float*)d_out;
  char* ws = (char*)d_ws;

  half_t* P2h = (half_t*)(ws + OFF_P2);
  half_t* P1h = (half_t*)(ws + OFF_P1);
  half_t* X3h = (half_t*)(ws + OFF_X3);
  float*  X4f = (float*)(ws + OFF_X4);
  half_t* wp2 = (half_t*)(ws + OFF_W2);
  half_t* wp3 = (half_t*)(ws + OFF_W3);
  half_t* wp4 = (half_t*)(ws + OFF_W4);
  half_t* wp1 = (half_t*)(ws + OFF_W1);

  pack_weights<<<432, 256, 0, stream>>>(w2, w3, w4, w1, wp2, wp3, wp4, wp1);
  conv1_mfma<<<dim3(32, 48, 8), 256, 0, stream>>>(input, wp1, b1, P1h);
  conv2_mfma<<<dim3(16, 48, 8), 256, 0, stream>>>(P1h, wp2, b2, P2h);
  conv3_mfma<<<dim3(8, 24, 8), 256, 0, stream>>>(P2h, wp3, b3, X3h);
  conv4_mfma<<<dim3(8, 24, 8), 256, 0, stream>>>(X3h, wp4, b4, X4f);
  conv5_res<<<1536, 256, 0, stream>>>(X4f, w5, b5, input, out);
}

// Round 7
// 458.788 us; speedup vs baseline: 1.2087x; 1.0213x over previous
//
#include <hip/hip_runtime.h>

// Res_MCNN_branch2 on gfx950 — all convs f16 MFMA implicit-GEMM (16x16x32).
// R7: sliding-window REGISTER caching of B-fragments (LDS was the per-CU
// bottleneck: 1 LDS pipe vs 4 MFMA pipes; old mix capped MfmaUtil at ~30%).
// Fragments for taps (ky,kx) overlap: per-ky 2-row (conv2/3/4) or 4-row (conv1)
// windows over 6 columns, parity-indexed slots so the unrolled loop has no
// register moves; only the entering row is re-read from LDS each ky.
// conv3/conv4 N is phase-mapped like conv2 (pure permutation; no pooling).
// Weights always read per-tap from global (packed, coalesced 16B/lane, L2-hot).
// LDS bank rule: pixel records 40/72 halves (16B-mult, not 128B-mult).

typedef _Float16 half_t;
typedef _Float16 half8 __attribute__((ext_vector_type(8)));
typedef float floatx4 __attribute__((ext_vector_type(4)));

#define IN_H 768
#define IN_W 1024
#define P1H 384
#define P1W 512
#define P2H 192
#define P2W 256

// workspace offsets (bytes)
#define OFF_P2 0ULL                 // f16 [8][192][256][64]  = 50,331,648
#define OFF_P1 50331648ULL          // f16 [8][384][512][32]  = 100,663,296
#define OFF_X3 50331648ULL          // reuse P1 region after conv2
#define OFF_X4 0ULL                 // fp32 [8][192][256][10] reuse P2 region after conv3
#define OFF_W2 150994944ULL         // f16 [25][48][32] = 76,800 el
#define OFF_W3 151072768ULL         // f16 [25][32][64] = 102,400 el
#define OFF_W4 151175168ULL         // f16 [25][16][32] = 25,600 el
#define OFF_W1 151226368ULL         // f16 [7][32][32]  = 7,168 el

union PK4 { half_t h[4]; uint2 u; };
union U8 { half8 v; uint2 u[2]; };

// ---------------- weight pre-pack (fp32 OIHW -> f16 packed, linear) ----------------
__global__ __launch_bounds__(256) void pack_weights(
    const float* __restrict__ w2, const float* __restrict__ w3,
    const float* __restrict__ w4, const float* __restrict__ w1,
    half_t* __restrict__ wp2, half_t* __restrict__ wp3, half_t* __restrict__ wp4,
    half_t* __restrict__ wp1)
{
  int t = blockIdx.x * 256 + threadIdx.x;
  if (t < 38400) {                       // conv2: [25][48][32]
    int tap = t / 1536, r = t % 1536, oc = r >> 5, c = r & 31;
    float v = (oc < 40 && c < 20) ? w2[(oc * 20 + c) * 25 + tap] : 0.f;
    wp2[t] = (half_t)v;
  } else if (t < 89600) {                // conv3: [25][32][64]
    int u = t - 38400;
    int tap = u / 2048, r = u % 2048, oc = r >> 6, c = r & 63;
    float v = (oc < 20 && c < 40) ? w3[(oc * 40 + c) * 25 + tap] : 0.f;
    wp3[u] = (half_t)v;
  } else if (t < 102400) {               // conv4: [25][16][32]
    int u = t - 89600;
    int tap = u / 512, r = u % 512, oc = r >> 5, c = r & 31;
    float v = (oc < 10 && c < 20) ? w4[(oc * 20 + c) * 25 + tap] : 0.f;
    wp4[u] = (half_t)v;
  } else if (t < 109568) {               // conv1: [7][32][32], k = kx*4+c
    int u = t - 102400;
    int ky = u / 1024, r = u % 1024, oc = r >> 5, k = r & 31;
    int kx = k >> 2, c = k & 3;
    float v = (oc < 20 && c < 3 && kx < 7) ? w1[((oc * 3 + c) * 7 + ky) * 7 + kx] : 0.f;
    wp1[u] = (half_t)v;
  }
}

// ---------------- conv1 (3->20, 7x7, pad 3) MFMA + relu + pool -> P1 f16 NHWC32 ----------------
// conv tile 16x32 -> pooled 8x16; oc padded 32 (2 M-tiles). K = kx*4+c, 7 ky steps.
// B window: frag[slot=rowmod4][phx] (2 px x 4c each), slides 1 row/ky: 40 b64 vs 112.
// A per-ky from global (14KB, L2-hot) — no weight LDS.
__global__ __launch_bounds__(256) void conv1_mfma(
    const float* __restrict__ in, const half_t* __restrict__ wp,
    const float* __restrict__ bias, half_t* __restrict__ P1)
{
  __shared__ __align__(16) half_t ltile[22 * 40 * 4];   // 7040 B, row stride 40 px
  const int b = blockIdx.z, ty0 = blockIdx.y * 16, tx0 = blockIdx.x * 32;
  const int tid = threadIdx.x;

  const float* p0 = in + (size_t)b * 3 * IN_H * IN_W;
  for (int i = tid; i < 880; i += 256) {          // 22 rows x 40 cols (38 real + 2 zero)
    int r = i / 40, c = i - r * 40;
    int gy = ty0 - 3 + r, gx = tx0 - 3 + c;
    float v0 = 0.f, v1 = 0.f, v2 = 0.f;
    if (c < 38 && gy >= 0 && gy < IN_H && gx >= 0 && gx < IN_W) {
      size_t o = (size_t)gy * IN_W + gx;
      v0 = p0[o];
      v1 = p0[o + IN_H * IN_W];
      v2 = p0[o + 2 * IN_H * IN_W];
    }
    PK4 pk;
    pk.h[0] = (half_t)v0; pk.h[1] = (half_t)v1;
    pk.h[2] = (half_t)v2; pk.h[3] = (half_t)0.f;
    *(uint2*)(ltile + (r * 40 + c) * 4) = pk.u;
  }
  __syncthreads();

  const int wv = tid >> 6, ln = tid & 63, q = ln >> 4, nl = ln & 15;
  // fragment address for tile row R, phase phx: (R*40 + 2nl+phx+2q)*4, 8 halves (2x b64)
  const int cbase = (2 * nl + 2 * q) * 4;
  U8 frag[4][2];
  #pragma unroll
  for (int d = 0; d < 4; ++d) {                  // init tile rows 4wv..4wv+3 -> slot d
    const half_t* rp = ltile + (4 * wv + d) * 160 + cbase;
    #pragma unroll
    for (int phx = 0; phx < 2; ++phx) {
      frag[d][phx].u[0] = *(const uint2*)(rp + phx * 4);
      frag[d][phx].u[1] = *(const uint2*)(rp + phx * 4 + 4);
    }
  }
  const half_t* wA = wp + nl * 32 + q * 8;
  floatx4 acc[2][8];
  #pragma unroll
  for (int mt = 0; mt < 2; ++mt)
    #pragma unroll
    for (int j = 0; j < 8; ++j) acc[mt][j] = (floatx4){0.f, 0.f, 0.f, 0.f};

  #pragma unroll
  for (int ky = 0; ky < 7; ++ky) {
    half8 A0 = *(const half8*)(wA + ky * 1024);
    half8 A1 = *(const half8*)(wA + ky * 1024 + 512);
    #pragma unroll
    for (int j = 0; j < 8; ++j) {
      const int g = j >> 2, ph = j & 3, phy = ph >> 1, phx = ph & 1;
      half8 B = frag[(2 * g + phy + ky) & 3][phx].v;
      acc[0][j] = __builtin_amdgcn_mfma_f32_16x16x32_f16(A0, B, acc[0][j], 0, 0, 0);
      acc[1][j] = __builtin_amdgcn_mfma_f32_16x16x32_f16(A1, B, acc[1][j], 0, 0, 0);
    }
    if (ky < 6) {                                // slide: row 4wv+ky+4 -> slot ky&3
      const half_t* rp = ltile + (4 * wv + ky + 4) * 160 + cbase;
      #pragma unroll
      for (int phx = 0; phx < 2; ++phx) {
        frag[ky & 3][phx].u[0] = *(const uint2*)(rp + phx * 4);
        frag[ky & 3][phx].u[1] = *(const uint2*)(rp + phx * 4 + 4);
      }
    }
  }

  floatx4 bv[2];
  #pragma unroll
  for (int mt = 0; mt < 2; ++mt)
    #pragma unroll
    for (int r = 0; r < 4; ++r) {
      int oc = mt * 16 + q * 4 + r;
      bv[mt][r] = (oc < 20) ? bias[oc] : 0.f;
    }
  const int pr0 = (ty0 >> 1) + wv * 2;
  const int pc = (tx0 >> 1) + nl;
  #pragma unroll
  for (int g = 0; g < 2; ++g) {
    size_t pxbase = (((size_t)b * P1H + pr0 + g) * P1W + pc) * 32;
    #pragma unroll
    for (int mt = 0; mt < 2; ++mt) {
      PK4 pk;
      #pragma unroll
      for (int r = 0; r < 4; ++r) {
        float x = fmaxf(fmaxf(acc[mt][g * 4 + 0][r], acc[mt][g * 4 + 1][r]),
                        fmaxf(acc[mt][g * 4 + 2][r], acc[mt][g * 4 + 3][r]));
        pk.h[r] = (half_t)fmaxf(x + bv[mt][r], 0.f);   // oc>=20: 0+0 -> 0 pad
      }
      *(uint2*)(P1 + pxbase + mt * 16 + q * 4) = pk.u;
    }
  }
}

// ---------------- conv2 (20->40, 5x5) MFMA + relu + pool -> P2 f16 NHWC64 ----------------
// conv tile 8x32 -> pooled 4x16. B window frag[rowmod2][6 cols]: 36 b128 vs 100.
__global__ __launch_bounds__(256) void conv2_mfma(
    const half_t* __restrict__ P1, const half_t* __restrict__ wp,
    const float* __restrict__ bias, half_t* __restrict__ P2)
{
  __shared__ __align__(16) half_t lin[12 * 36 * 40];   // 34560 B
  const int b = blockIdx.z, ty0 = blockIdx.y * 8, tx0 = blockIdx.x * 32;
  const int tid = threadIdx.x;
  for (int i = tid; i < 1728; i += 256) {              // 432 px x 4 parts
    int px = i >> 2, part = i & 3;
    int row = px / 36, col = px - row * 36;
    int gy = ty0 - 2 + row, gx = tx0 - 2 + col;
    uint4 v = make_uint4(0, 0, 0, 0);
    if (gy >= 0 && gy < P1H && gx >= 0 && gx < P1W)
      v = *(const uint4*)(P1 + (((size_t)b * P1H + gy) * P1W + gx) * 32 + part * 8);
    *(uint4*)(lin + px * 40 + part * 8) = v;
  }
  __syncthreads();

  const int wv = tid >> 6, ln = tid & 63, q = ln >> 4, nl = ln & 15;
  const int cbase = 2 * nl * 40 + q * 8;               // + row*1440 + c*40
  half8 frag[2][6];
  #pragma unroll
  for (int c = 0; c < 6; ++c) {
    frag[0][c] = *(const half8*)(lin + (2 * wv + 0) * 1440 + cbase + c * 40);
    frag[1][c] = *(const half8*)(lin + (2 * wv + 1) * 1440 + cbase + c * 40);
  }
  const half_t* wA = wp + nl * 32 + q * 8;
  floatx4 acc[3][4];
  #pragma unroll
  for (int mt = 0; mt < 3; ++mt)
    #pragma unroll
    for (int j = 0; j < 4; ++j) acc[mt][j] = (floatx4){0.f, 0.f, 0.f, 0.f};

  #pragma unroll
  for (int ky = 0; ky < 5; ++ky) {
    #pragma unroll
    for (int kx = 0; kx < 5; ++kx) {
      const int tap = ky * 5 + kx;
      half8 A0 = *(const half8*)(wA + tap * 1536);
      half8 A1 = *(const half8*)(wA + tap * 1536 + 512);
      half8 A2 = *(const half8*)(wA + tap * 1536 + 1024);
      #pragma unroll
      for (int j = 0; j < 4; ++j) {
        const int phy = j >> 1, phx = j & 1;
        half8 B = frag[(ky + phy) & 1][kx + phx];
        acc[0][j] = __builtin_amdgcn_mfma_f32_16x16x32_f16(A0, B, acc[0][j], 0, 0, 0);
        acc[1][j] = __builtin_amdgcn_mfma_f32_16x16x32_f16(A1, B, acc[1][j], 0, 0, 0);
        acc[2][j] = __builtin_amdgcn_mfma_f32_16x16x32_f16(A2, B, acc[2][j], 0, 0, 0);
      }
    }
    if (ky < 4) {                                      // slide: row 2wv+ky+2 -> slot ky&1
      const half_t* rp = lin + (2 * wv + ky + 2) * 1440 + cbase;
      #pragma unroll
      for (int c = 0; c < 6; ++c) frag[ky & 1][c] = *(const half8*)(rp + c * 40);
    }
  }

  floatx4 bv[3];
  #pragma unroll
  for (int mt = 0; mt < 3; ++mt)
    #pragma unroll
    for (int r = 0; r < 4; ++r) {
      int oc = mt * 16 + q * 4 + r;
      bv[mt][r] = (oc < 40) ? bias[oc] : 0.f;
    }
  const int pr = (ty0 >> 1) + wv;
  const int pc = (tx0 >> 1) + nl;
  size_t pxbase = (((size_t)b * P2H + pr) * P2W + pc) * 64;
  #pragma unroll
  for (int mt = 0; mt < 3; ++mt) {
    PK4 pk;
    #pragma unroll
    for (int r = 0; r < 4; ++r) {
      float x = fmaxf(fmaxf(acc[mt][0][r], acc[mt][1][r]),
                      fmaxf(acc[mt][2][r], acc[mt][3][r]));
      pk.h[r] = (half_t)fmaxf(x + bv[mt][r], 0.f);
    }
    *(uint2*)(P2 + pxbase + mt * 16 + q * 4) = pk.u;
  }
  if (q < 2)
    *(uint4*)(P2 + pxbase + 48 + q * 8) = make_uint4(0, 0, 0, 0);  // oc 48..63 = 0
}

// ---------------- conv3 (40->20, 5x5) MFMA + relu -> X3 f16 NHWC32 ----------------
// Phase-mapped N (no pool — pure permutation). Window frag[rowmod2][6][2cb].
__global__ __launch_bounds__(256) void conv3_mfma(
    const half_t* __restrict__ P2, const half_t* __restrict__ wp,
    const float* __restrict__ bias, half_t* __restrict__ X3)
{
  __shared__ __align__(16) half_t lin[12 * 36 * 72];   // 62208 B
  const int b = blockIdx.z, ty0 = blockIdx.y * 8, tx0 = blockIdx.x * 32;
  const int tid = threadIdx.x;
  for (int i = tid; i < 3456; i += 256) {
    int px = i >> 3, part = i & 7;
    int row = px / 36, col = px - row * 36;
    int gy = ty0 - 2 + row, gx = tx0 - 2 + col;
    uint4 v = make_uint4(0, 0, 0, 0);
    if (gy >= 0 && gy < P2H && gx >= 0 && gx < P2W)
      v = *(const uint4*)(P2 + (((size_t)b * P2H + gy) * P2W + gx) * 64 + part * 8);
    *(uint4*)(lin + px * 72 + part * 8) = v;
  }
  __syncthreads();

  const int wv = tid >> 6, ln = tid & 63, q = ln >> 4, nl = ln & 15;
  const int cbase = 2 * nl * 72 + q * 8;               // + row*2592 + c*72 + cb*32
  half8 frag[2][6][2];
  #pragma unroll
  for (int c = 0; c < 6; ++c)
    #pragma unroll
    for (int cb = 0; cb < 2; ++cb) {
      frag[0][c][cb] = *(const half8*)(lin + (2 * wv + 0) * 2592 + cbase + c * 72 + cb * 32);
      frag[1][c][cb] = *(const half8*)(lin + (2 * wv + 1) * 2592 + cbase + c * 72 + cb * 32);
    }
  const half_t* wA = wp + nl * 64 + q * 8;
  floatx4 acc[2][4];
  #pragma unroll
  for (int mt = 0; mt < 2; ++mt)
    #pragma unroll
    for (int j = 0; j < 4; ++j) acc[mt][j] = (floatx4){0.f, 0.f, 0.f, 0.f};

  #pragma unroll
  for (int ky = 0; ky < 5; ++ky) {
    #pragma unroll
    for (int kx = 0; kx < 5; ++kx) {
      const int tap = ky * 5 + kx;
      #pragma unroll
      for (int cb = 0; cb < 2; ++cb) {
        half8 A0 = *(const half8*)(wA + tap * 2048 + cb * 32);
        half8 A1 = *(const half8*)(wA + tap * 2048 + 1024 + cb * 32);
        #pragma unroll
        for (int j = 0; j < 4; ++j) {
          const int phy = j >> 1, phx = j & 1;
          half8 B = frag[(ky + phy) & 1][kx + phx][cb];
          acc[0][j] = __builtin_amdgcn_mfma_f32_16x16x32_f16(A0, B, acc[0][j], 0, 0, 0);
          acc[1][j] = __builtin_amdgcn_mfma_f32_16x16x32_f16(A1, B, acc[1][j], 0, 0, 0);
        }
      }
    }
    if (ky < 4) {
      const half_t* rp = lin + (2 * wv + ky + 2) * 2592 + cbase;
      #pragma unroll
      for (int c = 0; c < 6; ++c)
        #pragma unroll
        for (int cb = 0; cb < 2; ++cb)
          frag[ky & 1][c][cb] = *(const half8*)(rp + c * 72 + cb * 32);
    }
  }

  floatx4 bv[2];
  #pragma unroll
  for (int mt = 0; mt < 2; ++mt)
    #pragma unroll
    for (int r = 0; r < 4; ++r) {
      int oc = mt * 16 + q * 4 + r;
      bv[mt][r] = (oc < 20) ? bias[oc] : 0.f;
    }
  #pragma unroll
  for (int j = 0; j < 4; ++j) {
    const int phy = j >> 1, phx = j & 1;
    int y = ty0 + 2 * wv + phy, x = tx0 + 2 * nl + phx;
    size_t pxbase = (((size_t)b * P2H + y) * P2W + x) * 32;
    #pragma unroll
    for (int mt = 0; mt < 2; ++mt) {
      floatx4 v = acc[mt][j];
      PK4 pk;
      #pragma unroll
      for (int r = 0; r < 4; ++r) pk.h[r] = (half_t)fmaxf(v[r] + bv[mt][r], 0.f);
      *(uint2*)(X3 + pxbase + mt * 16 + q * 4) = pk.u;
    }
  }
}

// ---------------- conv4 (20->10, 5x5) MFMA + relu -> X4 fp32 NHWC10 ----------------
// Phase-mapped N, window frag[rowmod2][6]. mt=1 (oc padded 16).
__global__ __launch_bounds__(256) void conv4_mfma(
    const half_t* __restrict__ X3, const half_t* __restrict__ wp,
    const float* __restrict__ bias, float* __restrict__ X4)
{
  __shared__ __align__(16) half_t lin[12 * 36 * 40];   // 34560 B
  const int b = blockIdx.z, ty0 = blockIdx.y * 8, tx0 = blockIdx.x * 32;
  const int tid = threadIdx.x;
  for (int i = tid; i < 1728; i += 256) {
    int px = i >> 2, part = i & 3;
    int row = px / 36, col = px - row * 36;
    int gy = ty0 - 2 + row, gx = tx0 - 2 + col;
    uint4 v = make_uint4(0, 0, 0, 0);
    if (gy >= 0 && gy < P2H && gx >= 0 && gx < P2W)
      v = *(const uint4*)(X3 + (((size_t)b * P2H + gy) * P2W + gx) * 32 + part * 8);
    *(uint4*)(lin + px * 40 + part * 8) = v;
  }
  __syncthreads();

  const int wv = tid >> 6, ln = tid & 63, q = ln >> 4, nl = ln & 15;
  const int cbase = 2 * nl * 40 + q * 8;
  half8 frag[2][6];
  #pragma unroll
  for (int c = 0; c < 6; ++c) {
    frag[0][c] = *(const half8*)(lin + (2 * wv + 0) * 1440 + cbase + c * 40);
    frag[1][c] = *(const half8*)(lin + (2 * wv + 1) * 1440 + cbase + c * 40);
  }
  const half_t* wA = wp + nl * 32 + q * 8;
  floatx4 acc[4];
  #pragma unroll
  for (int j = 0; j < 4; ++j) acc[j] = (floatx4){0.f, 0.f, 0.f, 0.f};

  #pragma unroll
  for (int ky = 0; ky < 5; ++ky) {
    #pragma unroll
    for (int kx = 0; kx < 5; ++kx) {
      const int tap = ky * 5 + kx;
      half8 A = *(const half8*)(wA + tap * 512);
      #pragma unroll
      for (int j = 0; j < 4; ++j) {
        const int phy = j >> 1, phx = j & 1;
        half8 B = frag[(ky + phy) & 1][kx + phx];
        acc[j] = __builtin_amdgcn_mfma_f32_16x16x32_f16(A, B, acc[j], 0, 0, 0);
      }
    }
    if (ky < 4) {
      const half_t* rp = lin + (2 * wv + ky + 2) * 1440 + cbase;
      #pragma unroll
      for (int c = 0; c < 6; ++c) frag[ky & 1][c] = *(const half8*)(rp + c * 40);
    }
  }

  float bv[4];
  #pragma unroll
  for (int r = 0; r < 4; ++r) {
    int oc = q * 4 + r;
    bv[r] = (oc < 10) ? bias[oc] : 0.f;
  }
  #pragma unroll
  for (int j = 0; j < 4; ++j) {
    const int phy = j >> 1, phx = j & 1;
    int y = ty0 + 2 * wv + phy, x = tx0 + 2 * nl + phx;
    float* dst = X4 + (((size_t)b * P2H + y) * P2W + x) * 10;
    floatx4 v = acc[j];
    float r0 = fmaxf(v[0] + bv[0], 0.f), r1 = fmaxf(v[1] + bv[1], 0.f);
    float r2 = fmaxf(v[2] + bv[2], 0.f), r3 = fmaxf(v[3] + bv[3], 0.f);
    if (q < 2) {
      *(float2*)(dst + q * 4)     = make_float2(r0, r1);
      *(float2*)(dst + q * 4 + 2) = make_float2(r2, r3);
    } else if (q == 2) {
      *(float2*)(dst + 8) = make_float2(r0, r1);   // oc 8,9
    }
  }
}

// ---------------- conv5 (10->1, 1x1) + gray residual + relu ----------------
__global__ __launch_bounds__(256) void conv5_res(
    const float* __restrict__ X4, const float* __restrict__ w5,
    const float* __restrict__ b5, const float* __restrict__ in,
    float* __restrict__ out)
{
  const int idx = blockIdx.x * 256 + threadIdx.x;  // 0 .. 8*192*256-1
  const int j = idx & 255;
  const int bi = idx >> 8;
  const int i = bi % 192;
  const int b = bi / 192;
  const float* xp = X4 + (((size_t)b * P2H + i) * P2W + j) * 10;
  float sum = b5[0];
  #pragma unroll
  for (int c = 0; c < 10; ++c) sum += w5[c] * xp[c];
  const int r0 = 4 * i + 1, c0 = 4 * j + 1;
  float g = 0.f;
  #pragma unroll
  for (int ch = 0; ch < 3; ++ch) {
    const float coef = (ch == 0) ? 0.299f : ((ch == 1) ? 0.587f : 0.114f);
    const float* q = in + ((size_t)b * 3 + ch) * IN_H * IN_W;
    g += coef * (q[(size_t)r0 * IN_W + c0] + q[(size_t)r0 * IN_W + c0 + 1] +
                 q[(size_t)(r0 + 1) * IN_W + c0] + q[(size_t)(r0 + 1) * IN_W + c0 + 1]);
  }
  g *= 0.25f;
  out[idx] = fmaxf(sum + fmaxf(g, 0.f), 0.f);
}

extern "C" void kernel_launch(void* const* d_in, const int* in_sizes, int n_in,
                              void* d_out, int out_size, void* d_ws, size_t ws_size,
                              hipStream_t stream) {
  const float* input = (const float*)d_in[0];
  const float* w1 = (const float*)d_in[1];  const float* b1 = (const float*)d_in[2];
  const float* w2 = (const float*)d_in[3];  const float* b2 = (const float*)d_in[4];
  const float* w3 = (const float*)d_in[5];  const float* b3 = (const float*)d_in[6];
  const float* w4 = (const float*)d_in[7];  const float* b4 = (const float*)d_in[8];
  const float* w5 = (const float*)d_in[9];  const float* b5 = (const float*)d_in[10];
  float* out = (float*)d_out;
  char* ws = (char*)d_ws;

  half_t* P2h = (half_t*)(ws + OFF_P2);
  half_t* P1h = (half_t*)(ws + OFF_P1);
  half_t* X3h = (half_t*)(ws + OFF_X3);
  float*  X4f = (float*)(ws + OFF_X4);
  half_t* wp2 = (half_t*)(ws + OFF_W2);
  half_t* wp3 = (half_t*)(ws + OFF_W3);
  half_t* wp4 = (half_t*)(ws + OFF_W4);
  half_t* wp1 = (half_t*)(ws + OFF_W1);

  pack_weights<<<432, 256, 0, stream>>>(w2, w3, w4, w1, wp2, wp3, wp4, wp1);
  conv1_mfma<<<dim3(32, 48, 8), 256, 0, stream>>>(input, wp1, b1, P1h);
  conv2_mfma<<<dim3(16, 48, 8), 256, 0, stream>>>(P1h, wp2, b2, P2h);
  conv3_mfma<<<dim3(8, 24, 8), 256, 0, stream>>>(P2h, wp3, b3, X3h);
  conv4_mfma<<<dim3(8, 24, 8), 256, 0, stream>>>(X3h, wp4, b4, X4f);
  conv5_res<<<1536, 256, 0, stream>>>(X4f, w5, b5, input, out);
}

// Round 8
// 429.078 us; speedup vs baseline: 1.2924x; 1.0692x over previous
//
#include <hip/hip_runtime.h>

// Res_MCNN_branch2 on gfx950 — all convs f16 MFMA implicit-GEMM (16x16x32).
// R8: attack per-wave dependency stalls (R7 showed neither B-LDS nor L1 BW is
// the binder; MfmaUtil stuck ~35% = 58us floor / 144us measured).
//  (a) depth-1 A-prefetch via tap-parity register buffers in every conv kernel;
//  (b) conv2/conv4: N=128 px/wave (16x32 conv tile, 4-row x 6-col register
//      window, __launch_bounds__(256,2)) — halves A+B traffic and stall
//      exposure per MFMA.
// LDS bank rule: pixel records 40/72 halves (16B-mult, not 128B-mult).

typedef _Float16 half_t;
typedef _Float16 half8 __attribute__((ext_vector_type(8)));
typedef float floatx4 __attribute__((ext_vector_type(4)));

#define IN_H 768
#define IN_W 1024
#define P1H 384
#define P1W 512
#define P2H 192
#define P2W 256

// workspace offsets (bytes)
#define OFF_P2 0ULL                 // f16 [8][192][256][64]  = 50,331,648
#define OFF_P1 50331648ULL          // f16 [8][384][512][32]  = 100,663,296
#define OFF_X3 50331648ULL          // reuse P1 region after conv2
#define OFF_X4 0ULL                 // fp32 [8][192][256][10] reuse P2 region after conv3
#define OFF_W2 150994944ULL         // f16 [25][48][32] = 76,800 el
#define OFF_W3 151072768ULL         // f16 [25][32][64] = 102,400 el
#define OFF_W4 151175168ULL         // f16 [25][16][32] = 25,600 el
#define OFF_W1 151226368ULL         // f16 [7][32][32]  = 7,168 el

union PK4 { half_t h[4]; uint2 u; };
union U8 { half8 v; uint2 u[2]; };

// ---------------- weight pre-pack (fp32 OIHW -> f16 packed, linear) ----------------
__global__ __launch_bounds__(256) void pack_weights(
    const float* __restrict__ w2, const float* __restrict__ w3,
    const float* __restrict__ w4, const float* __restrict__ w1,
    half_t* __restrict__ wp2, half_t* __restrict__ wp3, half_t* __restrict__ wp4,
    half_t* __restrict__ wp1)
{
  int t = blockIdx.x * 256 + threadIdx.x;
  if (t < 38400) {                       // conv2: [25][48][32]
    int tap = t / 1536, r = t % 1536, oc = r >> 5, c = r & 31;
    float v = (oc < 40 && c < 20) ? w2[(oc * 20 + c) * 25 + tap] : 0.f;
    wp2[t] = (half_t)v;
  } else if (t < 89600) {                // conv3: [25][32][64]
    int u = t - 38400;
    int tap = u / 2048, r = u % 2048, oc = r >> 6, c = r & 63;
    float v = (oc < 20 && c < 40) ? w3[(oc * 40 + c) * 25 + tap] : 0.f;
    wp3[u] = (half_t)v;
  } else if (t < 102400) {               // conv4: [25][16][32]
    int u = t - 89600;
    int tap = u / 512, r = u % 512, oc = r >> 5, c = r & 31;
    float v = (oc < 10 && c < 20) ? w4[(oc * 20 + c) * 25 + tap] : 0.f;
    wp4[u] = (half_t)v;
  } else if (t < 109568) {               // conv1: [7][32][32], k = kx*4+c
    int u = t - 102400;
    int ky = u / 1024, r = u % 1024, oc = r >> 5, k = r & 31;
    int kx = k >> 2, c = k & 3;
    float v = (oc < 20 && c < 3 && kx < 7) ? w1[((oc * 3 + c) * 7 + ky) * 7 + kx] : 0.f;
    wp1[u] = (half_t)v;
  }
}

// ---------------- conv1 (3->20, 7x7, pad 3) MFMA + relu + pool -> P1 f16 NHWC32 ----------------
// N=128/wave already; add depth-1 A prefetch (ky-parity buffers).
__global__ __launch_bounds__(256) void conv1_mfma(
    const float* __restrict__ in, const half_t* __restrict__ wp,
    const float* __restrict__ bias, half_t* __restrict__ P1)
{
  __shared__ __align__(16) half_t ltile[22 * 40 * 4];   // 7040 B, row stride 40 px
  const int b = blockIdx.z, ty0 = blockIdx.y * 16, tx0 = blockIdx.x * 32;
  const int tid = threadIdx.x;

  const float* p0 = in + (size_t)b * 3 * IN_H * IN_W;
  for (int i = tid; i < 880; i += 256) {          // 22 rows x 40 cols (38 real + 2 zero)
    int r = i / 40, c = i - r * 40;
    int gy = ty0 - 3 + r, gx = tx0 - 3 + c;
    float v0 = 0.f, v1 = 0.f, v2 = 0.f;
    if (c < 38 && gy >= 0 && gy < IN_H && gx >= 0 && gx < IN_W) {
      size_t o = (size_t)gy * IN_W + gx;
      v0 = p0[o];
      v1 = p0[o + IN_H * IN_W];
      v2 = p0[o + 2 * IN_H * IN_W];
    }
    PK4 pk;
    pk.h[0] = (half_t)v0; pk.h[1] = (half_t)v1;
    pk.h[2] = (half_t)v2; pk.h[3] = (half_t)0.f;
    *(uint2*)(ltile + (r * 40 + c) * 4) = pk.u;
  }
  __syncthreads();

  const int wv = tid >> 6, ln = tid & 63, q = ln >> 4, nl = ln & 15;
  const int cbase = (2 * nl + 2 * q) * 4;
  U8 frag[4][2];
  #pragma unroll
  for (int d = 0; d < 4; ++d) {                  // init tile rows 4wv..4wv+3 -> slot d
    const half_t* rp = ltile + (4 * wv + d) * 160 + cbase;
    #pragma unroll
    for (int phx = 0; phx < 2; ++phx) {
      frag[d][phx].u[0] = *(const uint2*)(rp + phx * 4);
      frag[d][phx].u[1] = *(const uint2*)(rp + phx * 4 + 4);
    }
  }
  const half_t* wA = wp + nl * 32 + q * 8;
  half8 Abuf[2][2];
  Abuf[0][0] = *(const half8*)(wA);
  Abuf[0][1] = *(const half8*)(wA + 512);
  floatx4 acc[2][8];
  #pragma unroll
  for (int mt = 0; mt < 2; ++mt)
    #pragma unroll
    for (int j = 0; j < 8; ++j) acc[mt][j] = (floatx4){0.f, 0.f, 0.f, 0.f};

  #pragma unroll
  for (int ky = 0; ky < 7; ++ky) {
    if (ky < 6) {
      Abuf[(ky + 1) & 1][0] = *(const half8*)(wA + (ky + 1) * 1024);
      Abuf[(ky + 1) & 1][1] = *(const half8*)(wA + (ky + 1) * 1024 + 512);
    }
    #pragma unroll
    for (int j = 0; j < 8; ++j) {
      const int g = j >> 2, ph = j & 3, phy = ph >> 1, phx = ph & 1;
      half8 B = frag[(2 * g + phy + ky) & 3][phx].v;
      acc[0][j] = __builtin_amdgcn_mfma_f32_16x16x32_f16(Abuf[ky & 1][0], B, acc[0][j], 0, 0, 0);
      acc[1][j] = __builtin_amdgcn_mfma_f32_16x16x32_f16(Abuf[ky & 1][1], B, acc[1][j], 0, 0, 0);
    }
    if (ky < 6) {                                // slide: row 4wv+ky+4 -> slot ky&3
      const half_t* rp = ltile + (4 * wv + ky + 4) * 160 + cbase;
      #pragma unroll
      for (int phx = 0; phx < 2; ++phx) {
        frag[ky & 3][phx].u[0] = *(const uint2*)(rp + phx * 4);
        frag[ky & 3][phx].u[1] = *(const uint2*)(rp + phx * 4 + 4);
      }
    }
  }

  floatx4 bv[2];
  #pragma unroll
  for (int mt = 0; mt < 2; ++mt)
    #pragma unroll
    for (int r = 0; r < 4; ++r) {
      int oc = mt * 16 + q * 4 + r;
      bv[mt][r] = (oc < 20) ? bias[oc] : 0.f;
    }
  const int pr0 = (ty0 >> 1) + wv * 2;
  const int pc = (tx0 >> 1) + nl;
  #pragma unroll
  for (int g = 0; g < 2; ++g) {
    size_t pxbase = (((size_t)b * P1H + pr0 + g) * P1W + pc) * 32;
    #pragma unroll
    for (int mt = 0; mt < 2; ++mt) {
      PK4 pk;
      #pragma unroll
      for (int r = 0; r < 4; ++r) {
        float x = fmaxf(fmaxf(acc[mt][g * 4 + 0][r], acc[mt][g * 4 + 1][r]),
                        fmaxf(acc[mt][g * 4 + 2][r], acc[mt][g * 4 + 3][r]));
        pk.h[r] = (half_t)fmaxf(x + bv[mt][r], 0.f);   // oc>=20: 0+0 -> 0 pad
      }
      *(uint2*)(P1 + pxbase + mt * 16 + q * 4) = pk.u;
    }
  }
}

// ---------------- conv2 (20->40, 5x5) MFMA + relu + pool -> P2 f16 NHWC64 ----------------
// N=128/wave: 16x32 conv tile, wave wv covers conv rows 4wv..4wv+3.
// j = g*4 + phy*2 + phx; window frag[4 rows][6 cols]; A depth-1 prefetch.
__global__ __launch_bounds__(256, 2) void conv2_mfma(
    const half_t* __restrict__ P1, const half_t* __restrict__ wp,
    const float* __restrict__ bias, half_t* __restrict__ P2)
{
  __shared__ __align__(16) half_t lin[20 * 36 * 40];   // 57600 B
  const int b = blockIdx.z, ty0 = blockIdx.y * 16, tx0 = blockIdx.x * 32;
  const int tid = threadIdx.x;
  for (int i = tid; i < 2880; i += 256) {              // 720 px x 4 parts
    int px = i >> 2, part = i & 3;
    int row = px / 36, col = px - row * 36;
    int gy = ty0 - 2 + row, gx = tx0 - 2 + col;
    uint4 v = make_uint4(0, 0, 0, 0);
    if (gy >= 0 && gy < P1H && gx >= 0 && gx < P1W)
      v = *(const uint4*)(P1 + (((size_t)b * P1H + gy) * P1W + gx) * 32 + part * 8);
    *(uint4*)(lin + px * 40 + part * 8) = v;
  }
  __syncthreads();

  const int wv = tid >> 6, ln = tid & 63, q = ln >> 4, nl = ln & 15;
  const int cbase = 2 * nl * 40 + q * 8;               // + row*1440 + c*40
  half8 frag[4][6];
  #pragma unroll
  for (int d = 0; d < 4; ++d) {
    const half_t* rp = lin + (4 * wv + d) * 1440 + cbase;
    #pragma unroll
    for (int c = 0; c < 6; ++c) frag[d][c] = *(const half8*)(rp + c * 40);
  }
  const half_t* wA = wp + nl * 32 + q * 8;
  half8 Abuf[2][3];
  #pragma unroll
  for (int mt = 0; mt < 3; ++mt) Abuf[0][mt] = *(const half8*)(wA + mt * 512);
  floatx4 acc[3][8];
  #pragma unroll
  for (int mt = 0; mt < 3; ++mt)
    #pragma unroll
    for (int j = 0; j < 8; ++j) acc[mt][j] = (floatx4){0.f, 0.f, 0.f, 0.f};

  #pragma unroll
  for (int ky = 0; ky < 5; ++ky) {
    #pragma unroll
    for (int kx = 0; kx < 5; ++kx) {
      const int tap = ky * 5 + kx;
      if (tap < 24) {
        #pragma unroll
        for (int mt = 0; mt < 3; ++mt)
          Abuf[(tap + 1) & 1][mt] = *(const half8*)(wA + (tap + 1) * 1536 + mt * 512);
      }
      #pragma unroll
      for (int j = 0; j < 8; ++j) {
        const int g = j >> 2, ph = j & 3, phy = ph >> 1, phx = ph & 1;
        half8 B = frag[(2 * g + phy + ky) & 3][kx + phx];
        acc[0][j] = __builtin_amdgcn_mfma_f32_16x16x32_f16(Abuf[tap & 1][0], B, acc[0][j], 0, 0, 0);
        acc[1][j] = __builtin_amdgcn_mfma_f32_16x16x32_f16(Abuf[tap & 1][1], B, acc[1][j], 0, 0, 0);
        acc[2][j] = __builtin_amdgcn_mfma_f32_16x16x32_f16(Abuf[tap & 1][2], B, acc[2][j], 0, 0, 0);
      }
    }
    if (ky < 4) {                                      // slide: row 4wv+ky+4 -> slot ky&3
      const half_t* rp = lin + (4 * wv + ky + 4) * 1440 + cbase;
      #pragma unroll
      for (int c = 0; c < 6; ++c) frag[ky & 3][c] = *(const half8*)(rp + c * 40);
    }
  }

  floatx4 bv[3];
  #pragma unroll
  for (int mt = 0; mt < 3; ++mt)
    #pragma unroll
    for (int r = 0; r < 4; ++r) {
      int oc = mt * 16 + q * 4 + r;
      bv[mt][r] = (oc < 40) ? bias[oc] : 0.f;
    }
  const int pr0 = (ty0 >> 1) + 2 * wv;
  const int pc = (tx0 >> 1) + nl;
  #pragma unroll
  for (int g = 0; g < 2; ++g) {
    size_t pxbase = (((size_t)b * P2H + pr0 + g) * P2W + pc) * 64;
    #pragma unroll
    for (int mt = 0; mt < 3; ++mt) {
      PK4 pk;
      #pragma unroll
      for (int r = 0; r < 4; ++r) {
        float x = fmaxf(fmaxf(acc[mt][g * 4 + 0][r], acc[mt][g * 4 + 1][r]),
                        fmaxf(acc[mt][g * 4 + 2][r], acc[mt][g * 4 + 3][r]));
        pk.h[r] = (half_t)fmaxf(x + bv[mt][r], 0.f);
      }
      *(uint2*)(P2 + pxbase + mt * 16 + q * 4) = pk.u;
    }
    if (q < 2)
      *(uint4*)(P2 + pxbase + 48 + q * 8) = make_uint4(0, 0, 0, 0);  // oc 48..63 = 0
  }
}

// ---------------- conv3 (40->20, 5x5) MFMA + relu -> X3 f16 NHWC32 ----------------
// Window frag[2][6][2cb] + A depth-1 prefetch (tap-parity).
__global__ __launch_bounds__(256, 2) void conv3_mfma(
    const half_t* __restrict__ P2, const half_t* __restrict__ wp,
    const float* __restrict__ bias, half_t* __restrict__ X3)
{
  __shared__ __align__(16) half_t lin[12 * 36 * 72];   // 62208 B
  const int b = blockIdx.z, ty0 = blockIdx.y * 8, tx0 = blockIdx.x * 32;
  const int tid = threadIdx.x;
  for (int i = tid; i < 3456; i += 256) {
    int px = i >> 3, part = i & 7;
    int row = px / 36, col = px - row * 36;
    int gy = ty0 - 2 + row, gx = tx0 - 2 + col;
    uint4 v = make_uint4(0, 0, 0, 0);
    if (gy >= 0 && gy < P2H && gx >= 0 && gx < P2W)
      v = *(const uint4*)(P2 + (((size_t)b * P2H + gy) * P2W + gx) * 64 + part * 8);
    *(uint4*)(lin + px * 72 + part * 8) = v;
  }
  __syncthreads();

  const int wv = tid >> 6, ln = tid & 63, q = ln >> 4, nl = ln & 15;
  const int cbase = 2 * nl * 72 + q * 8;               // + row*2592 + c*72 + cb*32
  half8 frag[2][6][2];
  #pragma unroll
  for (int c = 0; c < 6; ++c)
    #pragma unroll
    for (int cb = 0; cb < 2; ++cb) {
      frag[0][c][cb] = *(const half8*)(lin + (2 * wv + 0) * 2592 + cbase + c * 72 + cb * 32);
      frag[1][c][cb] = *(const half8*)(lin + (2 * wv + 1) * 2592 + cbase + c * 72 + cb * 32);
    }
  const half_t* wA = wp + nl * 64 + q * 8;
  half8 Abuf[2][2][2];                                 // [parity][mt][cb]
  #pragma unroll
  for (int mt = 0; mt < 2; ++mt)
    #pragma unroll
    for (int cb = 0; cb < 2; ++cb)
      Abuf[0][mt][cb] = *(const half8*)(wA + mt * 1024 + cb * 32);
  floatx4 acc[2][4];
  #pragma unroll
  for (int mt = 0; mt < 2; ++mt)
    #pragma unroll
    for (int j = 0; j < 4; ++j) acc[mt][j] = (floatx4){0.f, 0.f, 0.f, 0.f};

  #pragma unroll
  for (int ky = 0; ky < 5; ++ky) {
    #pragma unroll
    for (int kx = 0; kx < 5; ++kx) {
      const int tap = ky * 5 + kx;
      if (tap < 24) {
        #pragma unroll
        for (int mt = 0; mt < 2; ++mt)
          #pragma unroll
          for (int cb = 0; cb < 2; ++cb)
            Abuf[(tap + 1) & 1][mt][cb] =
                *(const half8*)(wA + (tap + 1) * 2048 + mt * 1024 + cb * 32);
      }
      #pragma unroll
      for (int cb = 0; cb < 2; ++cb)
        #pragma unroll
        for (int j = 0; j < 4; ++j) {
          const int phy = j >> 1, phx = j & 1;
          half8 B = frag[(ky + phy) & 1][kx + phx][cb];
          acc[0][j] = __builtin_amdgcn_mfma_f32_16x16x32_f16(Abuf[tap & 1][0][cb], B, acc[0][j], 0, 0, 0);
          acc[1][j] = __builtin_amdgcn_mfma_f32_16x16x32_f16(Abuf[tap & 1][1][cb], B, acc[1][j], 0, 0, 0);
        }
    }
    if (ky < 4) {
      const half_t* rp = lin + (2 * wv + ky + 2) * 2592 + cbase;
      #pragma unroll
      for (int c = 0; c < 6; ++c)
        #pragma unroll
        for (int cb = 0; cb < 2; ++cb)
          frag[ky & 1][c][cb] = *(const half8*)(rp + c * 72 + cb * 32);
    }
  }

  floatx4 bv[2];
  #pragma unroll
  for (int mt = 0; mt < 2; ++mt)
    #pragma unroll
    for (int r = 0; r < 4; ++r) {
      int oc = mt * 16 + q * 4 + r;
      bv[mt][r] = (oc < 20) ? bias[oc] : 0.f;
    }
  #pragma unroll
  for (int j = 0; j < 4; ++j) {
    const int phy = j >> 1, phx = j & 1;
    int y = ty0 + 2 * wv + phy, x = tx0 + 2 * nl + phx;
    size_t pxbase = (((size_t)b * P2H + y) * P2W + x) * 32;
    #pragma unroll
    for (int mt = 0; mt < 2; ++mt) {
      floatx4 v = acc[mt][j];
      PK4 pk;
      #pragma unroll
      for (int r = 0; r < 4; ++r) pk.h[r] = (half_t)fmaxf(v[r] + bv[mt][r], 0.f);
      *(uint2*)(X3 + pxbase + mt * 16 + q * 4) = pk.u;
    }
  }
}

// ---------------- conv4 (20->10, 5x5) MFMA + relu -> X4 fp32 NHWC10 ----------------
// N=128/wave: 16x32 tile, window frag[4][6], A depth-1 prefetch. mt=1.
__global__ __launch_bounds__(256, 2) void conv4_mfma(
    const half_t* __restrict__ X3, const half_t* __restrict__ wp,
    const float* __restrict__ bias, float* __restrict__ X4)
{
  __shared__ __align__(16) half_t lin[20 * 36 * 40];   // 57600 B
  const int b = blockIdx.z, ty0 = blockIdx.y * 16, tx0 = blockIdx.x * 32;
  const int tid = threadIdx.x;
  for (int i = tid; i < 2880; i += 256) {
    int px = i >> 2, part = i & 3;
    int row = px / 36, col = px - row * 36;
    int gy = ty0 - 2 + row, gx = tx0 - 2 + col;
    uint4 v = make_uint4(0, 0, 0, 0);
    if (gy >= 0 && gy < P2H && gx >= 0 && gx < P2W)
      v = *(const uint4*)(X3 + (((size_t)b * P2H + gy) * P2W + gx) * 32 + part * 8);
    *(uint4*)(lin + px * 40 + part * 8) = v;
  }
  __syncthreads();

  const int wv = tid >> 6, ln = tid & 63, q = ln >> 4, nl = ln & 15;
  const int cbase = 2 * nl * 40 + q * 8;
  half8 frag[4][6];
  #pragma unroll
  for (int d = 0; d < 4; ++d) {
    const half_t* rp = lin + (4 * wv + d) * 1440 + cbase;
    #pragma unroll
    for (int c = 0; c < 6; ++c) frag[d][c] = *(const half8*)(rp + c * 40);
  }
  const half_t* wA = wp + nl * 32 + q * 8;
  half8 Abuf[2];
  Abuf[0] = *(const half8*)(wA);
  floatx4 acc[8];
  #pragma unroll
  for (int j = 0; j < 8; ++j) acc[j] = (floatx4){0.f, 0.f, 0.f, 0.f};

  #pragma unroll
  for (int ky = 0; ky < 5; ++ky) {
    #pragma unroll
    for (int kx = 0; kx < 5; ++kx) {
      const int tap = ky * 5 + kx;
      if (tap < 24) Abuf[(tap + 1) & 1] = *(const half8*)(wA + (tap + 1) * 512);
      #pragma unroll
      for (int j = 0; j < 8; ++j) {
        const int g = j >> 2, ph = j & 3, phy = ph >> 1, phx = ph & 1;
        half8 B = frag[(2 * g + phy + ky) & 3][kx + phx];
        acc[j] = __builtin_amdgcn_mfma_f32_16x16x32_f16(Abuf[tap & 1], B, acc[j], 0, 0, 0);
      }
    }
    if (ky < 4) {
      const half_t* rp = lin + (4 * wv + ky + 4) * 1440 + cbase;
      #pragma unroll
      for (int c = 0; c < 6; ++c) frag[ky & 3][c] = *(const half8*)(rp + c * 40);
    }
  }

  float bv[4];
  #pragma unroll
  for (int r = 0; r < 4; ++r) {
    int oc = q * 4 + r;
    bv[r] = (oc < 10) ? bias[oc] : 0.f;
  }
  #pragma unroll
  for (int j = 0; j < 8; ++j) {
    const int g = j >> 2, ph = j & 3, phy = ph >> 1, phx = ph & 1;
    int y = ty0 + 4 * wv + 2 * g + phy, x = tx0 + 2 * nl + phx;
    float* dst = X4 + (((size_t)b * P2H + y) * P2W + x) * 10;
    floatx4 v = acc[j];
    float r0 = fmaxf(v[0] + bv[0], 0.f), r1 = fmaxf(v[1] + bv[1], 0.f);
    float r2 = fmaxf(v[2] + bv[2], 0.f), r3 = fmaxf(v[3] + bv[3], 0.f);
    if (q < 2) {
      *(float2*)(dst + q * 4)     = make_float2(r0, r1);
      *(float2*)(dst + q * 4 + 2) = make_float2(r2, r3);
    } else if (q == 2) {
      *(float2*)(dst + 8) = make_float2(r0, r1);   // oc 8,9
    }
  }
}

// ---------------- conv5 (10->1, 1x1) + gray residual + relu ----------------
__global__ __launch_bounds__(256) void conv5_res(
    const float* __restrict__ X4, const float* __restrict__ w5,
    const float* __restrict__ b5, const float* __restrict__ in,
    float* __restrict__ out)
{
  const int idx = blockIdx.x * 256 + threadIdx.x;  // 0 .. 8*192*256-1
  const int j = idx & 255;
  const int bi = idx >> 8;
  const int i = bi % 192;
  const int b = bi / 192;
  const float* xp = X4 + (((size_t)b * P2H + i) * P2W + j) * 10;
  float sum = b5[0];
  #pragma unroll
  for (int c = 0; c < 10; ++c) sum += w5[c] * xp[c];
  const int r0 = 4 * i + 1, c0 = 4 * j + 1;
  float g = 0.f;
  #pragma unroll
  for (int ch = 0; ch < 3; ++ch) {
    const float coef = (ch == 0) ? 0.299f : ((ch == 1) ? 0.587f : 0.114f);
    const float* q = in + ((size_t)b * 3 + ch) * IN_H * IN_W;
    g += coef * (q[(size_t)r0 * IN_W + c0] + q[(size_t)r0 * IN_W + c0 + 1] +
                 q[(size_t)(r0 + 1) * IN_W + c0] + q[(size_t)(r0 + 1) * IN_W + c0 + 1]);
  }
  g *= 0.25f;
  out[idx] = fmaxf(sum + fmaxf(g, 0.f), 0.f);
}

extern "C" void kernel_launch(void* const* d_in, const int* in_sizes, int n_in,
                              void* d_out, int out_size, void* d_ws, size_t ws_size,
                              hipStream_t stream) {
  const float* input = (const float*)d_in[0];
  const float* w1 = (const float*)d_in[1];  const float* b1 = (const float*)d_in[2];
  const float* w2 = (const float*)d_in[3];  const float* b2 = (const float*)d_in[4];
  const float* w3 = (const float*)d_in[5];  const float* b3 = (const float*)d_in[6];
  const float* w4 = (const float*)d_in[7];  const float* b4 = (const float*)d_in[8];
  const float* w5 = (const float*)d_in[9];  const float* b5 = (const float*)d_in[10];
  float* out = (float*)d_out;
  char* ws = (char*)d_ws;

  half_t* P2h = (half_t*)(ws + OFF_P2);
  half_t* P1h = (half_t*)(ws + OFF_P1);
  half_t* X3h = (half_t*)(ws + OFF_X3);
  float*  X4f = (float*)(ws + OFF_X4);
  half_t* wp2 = (half_t*)(ws + OFF_W2);
  half_t* wp3 = (half_t*)(ws + OFF_W3);
  half_t* wp4 = (half_t*)(ws + OFF_W4);
  half_t* wp1 = (half_t*)(ws + OFF_W1);

  pack_weights<<<432, 256, 0, stream>>>(w2, w3, w4, w1, wp2, wp3, wp4, wp1);
  conv1_mfma<<<dim3(32, 48, 8), 256, 0, stream>>>(input, wp1, b1, P1h);
  conv2_mfma<<<dim3(16, 24, 8), 256, 0, stream>>>(P1h, wp2, b2, P2h);
  conv3_mfma<<<dim3(8, 24, 8), 256, 0, stream>>>(P2h, wp3, b3, X3h);
  conv4_mfma<<<dim3(8, 12, 8), 256, 0, stream>>>(X3h, wp4, b4, X4f);
  conv5_res<<<1536, 256, 0, stream>>>(X4f, w5, b5, input, out);
}

// Round 9
// 410.345 us; speedup vs baseline: 1.3514x; 1.0457x over previous
//
#include <hip/hip_runtime.h>

// Res_MCNN_branch2 on gfx950 — all convs f16 MFMA implicit-GEMM (16x16x32).
// R9: conv1 double-pass tile — one staging phase (38x40 region, 12.2 KB LDS,
// halo 1.41x vs 1.63x) feeds TWO K-loop passes (conv rows 16p+..), halving the
// staging/barrier share that capped MfmaUtil at 29%. conv5 gray reads become
// lane-contiguous float4 loads (cols 4j..4j+3 per lane j = perfectly coalesced).
// conv2/3/4 unchanged from R8 (N=128/wave, reg window, depth-1 A prefetch).
// LDS bank rule: pixel records 40/72 halves (16B-mult, not 128B-mult).

typedef _Float16 half_t;
typedef _Float16 half8 __attribute__((ext_vector_type(8)));
typedef float floatx4 __attribute__((ext_vector_type(4)));

#define IN_H 768
#define IN_W 1024
#define P1H 384
#define P1W 512
#define P2H 192
#define P2W 256

// workspace offsets (bytes)
#define OFF_P2 0ULL                 // f16 [8][192][256][64]  = 50,331,648
#define OFF_P1 50331648ULL          // f16 [8][384][512][32]  = 100,663,296
#define OFF_X3 50331648ULL          // reuse P1 region after conv2
#define OFF_X4 0ULL                 // fp32 [8][192][256][10] reuse P2 region after conv3
#define OFF_W2 150994944ULL         // f16 [25][48][32] = 76,800 el
#define OFF_W3 151072768ULL         // f16 [25][32][64] = 102,400 el
#define OFF_W4 151175168ULL         // f16 [25][16][32] = 25,600 el
#define OFF_W1 151226368ULL         // f16 [7][32][32]  = 7,168 el

union PK4 { half_t h[4]; uint2 u; };
union U8 { half8 v; uint2 u[2]; };

// ---------------- weight pre-pack (fp32 OIHW -> f16 packed, linear) ----------------
__global__ __launch_bounds__(256) void pack_weights(
    const float* __restrict__ w2, const float* __restrict__ w3,
    const float* __restrict__ w4, const float* __restrict__ w1,
    half_t* __restrict__ wp2, half_t* __restrict__ wp3, half_t* __restrict__ wp4,
    half_t* __restrict__ wp1)
{
  int t = blockIdx.x * 256 + threadIdx.x;
  if (t < 38400) {                       // conv2: [25][48][32]
    int tap = t / 1536, r = t % 1536, oc = r >> 5, c = r & 31;
    float v = (oc < 40 && c < 20) ? w2[(oc * 20 + c) * 25 + tap] : 0.f;
    wp2[t] = (half_t)v;
  } else if (t < 89600) {                // conv3: [25][32][64]
    int u = t - 38400;
    int tap = u / 2048, r = u % 2048, oc = r >> 6, c = r & 63;
    float v = (oc < 20 && c < 40) ? w3[(oc * 40 + c) * 25 + tap] : 0.f;
    wp3[u] = (half_t)v;
  } else if (t < 102400) {               // conv4: [25][16][32]
    int u = t - 89600;
    int tap = u / 512, r = u % 512, oc = r >> 5, c = r & 31;
    float v = (oc < 10 && c < 20) ? w4[(oc * 20 + c) * 25 + tap] : 0.f;
    wp4[u] = (half_t)v;
  } else if (t < 109568) {               // conv1: [7][32][32], k = kx*4+c
    int u = t - 102400;
    int ky = u / 1024, r = u % 1024, oc = r >> 5, k = r & 31;
    int kx = k >> 2, c = k & 3;
    float v = (oc < 20 && c < 3 && kx < 7) ? w1[((oc * 3 + c) * 7 + ky) * 7 + kx] : 0.f;
    wp1[u] = (half_t)v;
  }
}

// ---------------- conv1 (3->20, 7x7, pad 3) MFMA + relu + pool -> P1 f16 NHWC32 ----------------
// 32-row tile, stage once (38x40 region), two K-loop passes p=0,1 over conv
// rows 16p+4wv..+3. Window frag[4 rows][2 phx] slides 1 row/ky; A depth-1 prefetch.
__global__ __launch_bounds__(256) void conv1_mfma(
    const float* __restrict__ in, const half_t* __restrict__ wp,
    const float* __restrict__ bias, half_t* __restrict__ P1)
{
  __shared__ __align__(16) half_t ltile[38 * 40 * 4];   // 12160 B, row stride 40 px
  const int b = blockIdx.z, ty0 = blockIdx.y * 32, tx0 = blockIdx.x * 32;
  const int tid = threadIdx.x;

  const float* p0 = in + (size_t)b * 3 * IN_H * IN_W;
  for (int i = tid; i < 1520; i += 256) {         // 38 rows x 40 cols (38 real + 2 zero)
    int r = i / 40, c = i - r * 40;
    int gy = ty0 - 3 + r, gx = tx0 - 3 + c;
    float v0 = 0.f, v1 = 0.f, v2 = 0.f;
    if (c < 38 && gy >= 0 && gy < IN_H && gx >= 0 && gx < IN_W) {
      size_t o = (size_t)gy * IN_W + gx;
      v0 = p0[o];
      v1 = p0[o + IN_H * IN_W];
      v2 = p0[o + 2 * IN_H * IN_W];
    }
    PK4 pk;
    pk.h[0] = (half_t)v0; pk.h[1] = (half_t)v1;
    pk.h[2] = (half_t)v2; pk.h[3] = (half_t)0.f;
    *(uint2*)(ltile + (r * 40 + c) * 4) = pk.u;
  }
  __syncthreads();

  const int wv = tid >> 6, ln = tid & 63, q = ln >> 4, nl = ln & 15;
  const int cbase = (2 * nl + 2 * q) * 4;
  const half_t* wA = wp + nl * 32 + q * 8;

  floatx4 bv[2];
  #pragma unroll
  for (int mt = 0; mt < 2; ++mt)
    #pragma unroll
    for (int r = 0; r < 4; ++r) {
      int oc = mt * 16 + q * 4 + r;
      bv[mt][r] = (oc < 20) ? bias[oc] : 0.f;
    }
  const int pc = (tx0 >> 1) + nl;

  #pragma unroll
  for (int p = 0; p < 2; ++p) {
    const int rbase = p * 16 + 4 * wv;            // ltile row of this pass/wave
    U8 frag[4][2];
    #pragma unroll
    for (int d = 0; d < 4; ++d) {
      const half_t* rp = ltile + (rbase + d) * 160 + cbase;
      #pragma unroll
      for (int phx = 0; phx < 2; ++phx) {
        frag[d][phx].u[0] = *(const uint2*)(rp + phx * 4);
        frag[d][phx].u[1] = *(const uint2*)(rp + phx * 4 + 4);
      }
    }
    half8 Abuf[2][2];
    Abuf[0][0] = *(const half8*)(wA);
    Abuf[0][1] = *(const half8*)(wA + 512);
    floatx4 acc[2][8];
    #pragma unroll
    for (int mt = 0; mt < 2; ++mt)
      #pragma unroll
      for (int j = 0; j < 8; ++j) acc[mt][j] = (floatx4){0.f, 0.f, 0.f, 0.f};

    #pragma unroll
    for (int ky = 0; ky < 7; ++ky) {
      if (ky < 6) {
        Abuf[(ky + 1) & 1][0] = *(const half8*)(wA + (ky + 1) * 1024);
        Abuf[(ky + 1) & 1][1] = *(const half8*)(wA + (ky + 1) * 1024 + 512);
      }
      #pragma unroll
      for (int j = 0; j < 8; ++j) {
        const int g = j >> 2, ph = j & 3, phy = ph >> 1, phx = ph & 1;
        half8 B = frag[(2 * g + phy + ky) & 3][phx].v;
        acc[0][j] = __builtin_amdgcn_mfma_f32_16x16x32_f16(Abuf[ky & 1][0], B, acc[0][j], 0, 0, 0);
        acc[1][j] = __builtin_amdgcn_mfma_f32_16x16x32_f16(Abuf[ky & 1][1], B, acc[1][j], 0, 0, 0);
      }
      if (ky < 6) {                               // slide: ltile row rbase+ky+4 -> slot ky&3
        const half_t* rp = ltile + (rbase + ky + 4) * 160 + cbase;
        #pragma unroll
        for (int phx = 0; phx < 2; ++phx) {
          frag[ky & 3][phx].u[0] = *(const uint2*)(rp + phx * 4);
          frag[ky & 3][phx].u[1] = *(const uint2*)(rp + phx * 4 + 4);
        }
      }
    }

    const int pr0 = (ty0 >> 1) + 8 * p + 2 * wv;
    #pragma unroll
    for (int g = 0; g < 2; ++g) {
      size_t pxbase = (((size_t)b * P1H + pr0 + g) * P1W + pc) * 32;
      #pragma unroll
      for (int mt = 0; mt < 2; ++mt) {
        PK4 pk;
        #pragma unroll
        for (int r = 0; r < 4; ++r) {
          float x = fmaxf(fmaxf(acc[mt][g * 4 + 0][r], acc[mt][g * 4 + 1][r]),
                          fmaxf(acc[mt][g * 4 + 2][r], acc[mt][g * 4 + 3][r]));
          pk.h[r] = (half_t)fmaxf(x + bv[mt][r], 0.f);   // oc>=20: 0+0 -> 0 pad
        }
        *(uint2*)(P1 + pxbase + mt * 16 + q * 4) = pk.u;
      }
    }
  }
}

// ---------------- conv2 (20->40, 5x5) MFMA + relu + pool -> P2 f16 NHWC64 ----------------
// N=128/wave: 16x32 conv tile, wave wv covers conv rows 4wv..4wv+3.
// j = g*4 + phy*2 + phx; window frag[4 rows][6 cols]; A depth-1 prefetch.
__global__ __launch_bounds__(256, 2) void conv2_mfma(
    const half_t* __restrict__ P1, const half_t* __restrict__ wp,
    const float* __restrict__ bias, half_t* __restrict__ P2)
{
  __shared__ __align__(16) half_t lin[20 * 36 * 40];   // 57600 B
  const int b = blockIdx.z, ty0 = blockIdx.y * 16, tx0 = blockIdx.x * 32;
  const int tid = threadIdx.x;
  for (int i = tid; i < 2880; i += 256) {              // 720 px x 4 parts
    int px = i >> 2, part = i & 3;
    int row = px / 36, col = px - row * 36;
    int gy = ty0 - 2 + row, gx = tx0 - 2 + col;
    uint4 v = make_uint4(0, 0, 0, 0);
    if (gy >= 0 && gy < P1H && gx >= 0 && gx < P1W)
      v = *(const uint4*)(P1 + (((size_t)b * P1H + gy) * P1W + gx) * 32 + part * 8);
    *(uint4*)(lin + px * 40 + part * 8) = v;
  }
  __syncthreads();

  const int wv = tid >> 6, ln = tid & 63, q = ln >> 4, nl = ln & 15;
  const int cbase = 2 * nl * 40 + q * 8;               // + row*1440 + c*40
  half8 frag[4][6];
  #pragma unroll
  for (int d = 0; d < 4; ++d) {
    const half_t* rp = lin + (4 * wv + d) * 1440 + cbase;
    #pragma unroll
    for (int c = 0; c < 6; ++c) frag[d][c] = *(const half8*)(rp + c * 40);
  }
  const half_t* wA = wp + nl * 32 + q * 8;
  half8 Abuf[2][3];
  #pragma unroll
  for (int mt = 0; mt < 3; ++mt) Abuf[0][mt] = *(const half8*)(wA + mt * 512);
  floatx4 acc[3][8];
  #pragma unroll
  for (int mt = 0; mt < 3; ++mt)
    #pragma unroll
    for (int j = 0; j < 8; ++j) acc[mt][j] = (floatx4){0.f, 0.f, 0.f, 0.f};

  #pragma unroll
  for (int ky = 0; ky < 5; ++ky) {
    #pragma unroll
    for (int kx = 0; kx < 5; ++kx) {
      const int tap = ky * 5 + kx;
      if (tap < 24) {
        #pragma unroll
        for (int mt = 0; mt < 3; ++mt)
          Abuf[(tap + 1) & 1][mt] = *(const half8*)(wA + (tap + 1) * 1536 + mt * 512);
      }
      #pragma unroll
      for (int j = 0; j < 8; ++j) {
        const int g = j >> 2, ph = j & 3, phy = ph >> 1, phx = ph & 1;
        half8 B = frag[(2 * g + phy + ky) & 3][kx + phx];
        acc[0][j] = __builtin_amdgcn_mfma_f32_16x16x32_f16(Abuf[tap & 1][0], B, acc[0][j], 0, 0, 0);
        acc[1][j] = __builtin_amdgcn_mfma_f32_16x16x32_f16(Abuf[tap & 1][1], B, acc[1][j], 0, 0, 0);
        acc[2][j] = __builtin_amdgcn_mfma_f32_16x16x32_f16(Abuf[tap & 1][2], B, acc[2][j], 0, 0, 0);
      }
    }
    if (ky < 4) {                                      // slide: row 4wv+ky+4 -> slot ky&3
      const half_t* rp = lin + (4 * wv + ky + 4) * 1440 + cbase;
      #pragma unroll
      for (int c = 0; c < 6; ++c) frag[ky & 3][c] = *(const half8*)(rp + c * 40);
    }
  }

  floatx4 bv[3];
  #pragma unroll
  for (int mt = 0; mt < 3; ++mt)
    #pragma unroll
    for (int r = 0; r < 4; ++r) {
      int oc = mt * 16 + q * 4 + r;
      bv[mt][r] = (oc < 40) ? bias[oc] : 0.f;
    }
  const int pr0 = (ty0 >> 1) + 2 * wv;
  const int pc = (tx0 >> 1) + nl;
  #pragma unroll
  for (int g = 0; g < 2; ++g) {
    size_t pxbase = (((size_t)b * P2H + pr0 + g) * P2W + pc) * 64;
    #pragma unroll
    for (int mt = 0; mt < 3; ++mt) {
      PK4 pk;
      #pragma unroll
      for (int r = 0; r < 4; ++r) {
        float x = fmaxf(fmaxf(acc[mt][g * 4 + 0][r], acc[mt][g * 4 + 1][r]),
                        fmaxf(acc[mt][g * 4 + 2][r], acc[mt][g * 4 + 3][r]));
        pk.h[r] = (half_t)fmaxf(x + bv[mt][r], 0.f);
      }
      *(uint2*)(P2 + pxbase + mt * 16 + q * 4) = pk.u;
    }
    if (q < 2)
      *(uint4*)(P2 + pxbase + 48 + q * 8) = make_uint4(0, 0, 0, 0);  // oc 48..63 = 0
  }
}

// ---------------- conv3 (40->20, 5x5) MFMA + relu -> X3 f16 NHWC32 ----------------
// Window frag[2][6][2cb] + A depth-1 prefetch (tap-parity).
__global__ __launch_bounds__(256, 2) void conv3_mfma(
    const half_t* __restrict__ P2, const half_t* __restrict__ wp,
    const float* __restrict__ bias, half_t* __restrict__ X3)
{
  __shared__ __align__(16) half_t lin[12 * 36 * 72];   // 62208 B
  const int b = blockIdx.z, ty0 = blockIdx.y * 8, tx0 = blockIdx.x * 32;
  const int tid = threadIdx.x;
  for (int i = tid; i < 3456; i += 256) {
    int px = i >> 3, part = i & 7;
    int row = px / 36, col = px - row * 36;
    int gy = ty0 - 2 + row, gx = tx0 - 2 + col;
    uint4 v = make_uint4(0, 0, 0, 0);
    if (gy >= 0 && gy < P2H && gx >= 0 && gx < P2W)
      v = *(const uint4*)(P2 + (((size_t)b * P2H + gy) * P2W + gx) * 64 + part * 8);
    *(uint4*)(lin + px * 72 + part * 8) = v;
  }
  __syncthreads();

  const int wv = tid >> 6, ln = tid & 63, q = ln >> 4, nl = ln & 15;
  const int cbase = 2 * nl * 72 + q * 8;               // + row*2592 + c*72 + cb*32
  half8 frag[2][6][2];
  #pragma unroll
  for (int c = 0; c < 6; ++c)
    #pragma unroll
    for (int cb = 0; cb < 2; ++cb) {
      frag[0][c][cb] = *(const half8*)(lin + (2 * wv + 0) * 2592 + cbase + c * 72 + cb * 32);
      frag[1][c][cb] = *(const half8*)(lin + (2 * wv + 1) * 2592 + cbase + c * 72 + cb * 32);
    }
  const half_t* wA = wp + nl * 64 + q * 8;
  half8 Abuf[2][2][2];                                 // [parity][mt][cb]
  #pragma unroll
  for (int mt = 0; mt < 2; ++mt)
    #pragma unroll
    for (int cb = 0; cb < 2; ++cb)
      Abuf[0][mt][cb] = *(const half8*)(wA + mt * 1024 + cb * 32);
  floatx4 acc[2][4];
  #pragma unroll
  for (int mt = 0; mt < 2; ++mt)
    #pragma unroll
    for (int j = 0; j < 4; ++j) acc[mt][j] = (floatx4){0.f, 0.f, 0.f, 0.f};

  #pragma unroll
  for (int ky = 0; ky < 5; ++ky) {
    #pragma unroll
    for (int kx = 0; kx < 5; ++kx) {
      const int tap = ky * 5 + kx;
      if (tap < 24) {
        #pragma unroll
        for (int mt = 0; mt < 2; ++mt)
          #pragma unroll
          for (int cb = 0; cb < 2; ++cb)
            Abuf[(tap + 1) & 1][mt][cb] =
                *(const half8*)(wA + (tap + 1) * 2048 + mt * 1024 + cb * 32);
      }
      #pragma unroll
      for (int cb = 0; cb < 2; ++cb)
        #pragma unroll
        for (int j = 0; j < 4; ++j) {
          const int phy = j >> 1, phx = j & 1;
          half8 B = frag[(ky + phy) & 1][kx + phx][cb];
          acc[0][j] = __builtin_amdgcn_mfma_f32_16x16x32_f16(Abuf[tap & 1][0][cb], B, acc[0][j], 0, 0, 0);
          acc[1][j] = __builtin_amdgcn_mfma_f32_16x16x32_f16(Abuf[tap & 1][1][cb], B, acc[1][j], 0, 0, 0);
        }
    }
    if (ky < 4) {
      const half_t* rp = lin + (2 * wv + ky + 2) * 2592 + cbase;
      #pragma unroll
      for (int c = 0; c < 6; ++c)
        #pragma unroll
        for (int cb = 0; cb < 2; ++cb)
          frag[ky & 1][c][cb] = *(const half8*)(rp + c * 72 + cb * 32);
    }
  }

  floatx4 bv[2];
  #pragma unroll
  for (int mt = 0; mt < 2; ++mt)
    #pragma unroll
    for (int r = 0; r < 4; ++r) {
      int oc = mt * 16 + q * 4 + r;
      bv[mt][r] = (oc < 20) ? bias[oc] : 0.f;
    }
  #pragma unroll
  for (int j = 0; j < 4; ++j) {
    const int phy = j >> 1, phx = j & 1;
    int y = ty0 + 2 * wv + phy, x = tx0 + 2 * nl + phx;
    size_t pxbase = (((size_t)b * P2H + y) * P2W + x) * 32;
    #pragma unroll
    for (int mt = 0; mt < 2; ++mt) {
      floatx4 v = acc[mt][j];
      PK4 pk;
      #pragma unroll
      for (int r = 0; r < 4; ++r) pk.h[r] = (half_t)fmaxf(v[r] + bv[mt][r], 0.f);
      *(uint2*)(X3 + pxbase + mt * 16 + q * 4) = pk.u;
    }
  }
}

// ---------------- conv4 (20->10, 5x5) MFMA + relu -> X4 fp32 NHWC10 ----------------
// N=128/wave: 16x32 tile, window frag[4][6], A depth-1 prefetch. mt=1.
__global__ __launch_bounds__(256, 2) void conv4_mfma(
    const half_t* __restrict__ X3, const half_t* __restrict__ wp,
    const float* __restrict__ bias, float* __restrict__ X4)
{
  __shared__ __align__(16) half_t lin[20 * 36 * 40];   // 57600 B
  const int b = blockIdx.z, ty0 = blockIdx.y * 16, tx0 = blockIdx.x * 32;
  const int tid = threadIdx.x;
  for (int i = tid; i < 2880; i += 256) {
    int px = i >> 2, part = i & 3;
    int row = px / 36, col = px - row * 36;
    int gy = ty0 - 2 + row, gx = tx0 - 2 + col;
    uint4 v = make_uint4(0, 0, 0, 0);
    if (gy >= 0 && gy < P2H && gx >= 0 && gx < P2W)
      v = *(const uint4*)(X3 + (((size_t)b * P2H + gy) * P2W + gx) * 32 + part * 8);
    *(uint4*)(lin + px * 40 + part * 8) = v;
  }
  __syncthreads();

  const int wv = tid >> 6, ln = tid & 63, q = ln >> 4, nl = ln & 15;
  const int cbase = 2 * nl * 40 + q * 8;
  half8 frag[4][6];
  #pragma unroll
  for (int d = 0; d < 4; ++d) {
    const half_t* rp = lin + (4 * wv + d) * 1440 + cbase;
    #pragma unroll
    for (int c = 0; c < 6; ++c) frag[d][c] = *(const half8*)(rp + c * 40);
  }
  const half_t* wA = wp + nl * 32 + q * 8;
  half8 Abuf[2];
  Abuf[0] = *(const half8*)(wA);
  floatx4 acc[8];
  #pragma unroll
  for (int j = 0; j < 8; ++j) acc[j] = (floatx4){0.f, 0.f, 0.f, 0.f};

  #pragma unroll
  for (int ky = 0; ky < 5; ++ky) {
    #pragma unroll
    for (int kx = 0; kx < 5; ++kx) {
      const int tap = ky * 5 + kx;
      if (tap < 24) Abuf[(tap + 1) & 1] = *(const half8*)(wA + (tap + 1) * 512);
      #pragma unroll
      for (int j = 0; j < 8; ++j) {
        const int g = j >> 2, ph = j & 3, phy = ph >> 1, phx = ph & 1;
        half8 B = frag[(2 * g + phy + ky) & 3][kx + phx];
        acc[j] = __builtin_amdgcn_mfma_f32_16x16x32_f16(Abuf[tap & 1], B, acc[j], 0, 0, 0);
      }
    }
    if (ky < 4) {
      const half_t* rp = lin + (4 * wv + ky + 4) * 1440 + cbase;
      #pragma unroll
      for (int c = 0; c < 6; ++c) frag[ky & 3][c] = *(const half8*)(rp + c * 40);
    }
  }

  float bv[4];
  #pragma unroll
  for (int r = 0; r < 4; ++r) {
    int oc = q * 4 + r;
    bv[r] = (oc < 10) ? bias[oc] : 0.f;
  }
  #pragma unroll
  for (int j = 0; j < 8; ++j) {
    const int g = j >> 2, ph = j & 3, phy = ph >> 1, phx = ph & 1;
    int y = ty0 + 4 * wv + 2 * g + phy, x = tx0 + 2 * nl + phx;
    float* dst = X4 + (((size_t)b * P2H + y) * P2W + x) * 10;
    floatx4 v = acc[j];
    float r0 = fmaxf(v[0] + bv[0], 0.f), r1 = fmaxf(v[1] + bv[1], 0.f);
    float r2 = fmaxf(v[2] + bv[2], 0.f), r3 = fmaxf(v[3] + bv[3], 0.f);
    if (q < 2) {
      *(float2*)(dst + q * 4)     = make_float2(r0, r1);
      *(float2*)(dst + q * 4 + 2) = make_float2(r2, r3);
    } else if (q == 2) {
      *(float2*)(dst + 8) = make_float2(r0, r1);   // oc 8,9
    }
  }
}

// ---------------- conv5 (10->1, 1x1) + gray residual + relu ----------------
// Gray loads as float4 at col 4j (lane j): 64 lanes = contiguous 1KB, coalesced.
__global__ __launch_bounds__(256) void conv5_res(
    const float* __restrict__ X4, const float* __restrict__ w5,
    const float* __restrict__ b5, const float* __restrict__ in,
    float* __restrict__ out)
{
  const int idx = blockIdx.x * 256 + threadIdx.x;  // 0 .. 8*192*256-1
  const int j = idx & 255;
  const int bi = idx >> 8;
  const int i = bi % 192;
  const int b = bi / 192;
  const float* xp = X4 + (((size_t)b * P2H + i) * P2W + j) * 10;
  float sum = b5[0];
  #pragma unroll
  for (int c = 0; c < 10; ++c) sum += w5[c] * xp[c];
  const int r0 = 4 * i + 1;
  const size_t cb = (size_t)r0 * IN_W + 4 * j;     // float4 covers cols 4j..4j+3
  float g = 0.f;
  #pragma unroll
  for (int ch = 0; ch < 3; ++ch) {
    const float coef = (ch == 0) ? 0.299f : ((ch == 1) ? 0.587f : 0.114f);
    const float* q = in + ((size_t)b * 3 + ch) * IN_H * IN_W;
    float4 a = *(const float4*)(q + cb);
    float4 d = *(const float4*)(q + cb + IN_W);
    g += coef * (a.y + a.z + d.y + d.z);           // cols 4j+1, 4j+2
  }
  g *= 0.25f;
  out[idx] = fmaxf(sum + fmaxf(g, 0.f), 0.f);
}

extern "C" void kernel_launch(void* const* d_in, const int* in_sizes, int n_in,
                              void* d_out, int out_size, void* d_ws, size_t ws_size,
                              hipStream_t stream) {
  const float* input = (const float*)d_in[0];
  const float* w1 = (const float*)d_in[1];  const float* b1 = (const float*)d_in[2];
  const float* w2 = (const float*)d_in[3];  const float* b2 = (const float*)d_in[4];
  const float* w3 = (const float*)d_in[5];  const float* b3 = (const float*)d_in[6];
  const float* w4 = (const float*)d_in[7];  const float* b4 = (const float*)d_in[8];
  const float* w5 = (const float*)d_in[9];  const float* b5 = (const float*)d_in[10];
  float* out = (float*)d_out;
  char* ws = (char*)d_ws;

  half_t* P2h = (half_t*)(ws + OFF_P2);
  half_t* P1h = (half_t*)(ws + OFF_P1);
  half_t* X3h = (half_t*)(ws + OFF_X3);
  float*  X4f = (float*)(ws + OFF_X4);
  half_t* wp2 = (half_t*)(ws + OFF_W2);
  half_t* wp3 = (half_t*)(ws + OFF_W3);
  half_t* wp4 = (half_t*)(ws + OFF_W4);
  half_t* wp1 = (half_t*)(ws + OFF_W1);

  pack_weights<<<432, 256, 0, stream>>>(w2, w3, w4, w1, wp2, wp3, wp4, wp1);
  conv1_mfma<<<dim3(32, 24, 8), 256, 0, stream>>>(input, wp1, b1, P1h);
  conv2_mfma<<<dim3(16, 24, 8), 256, 0, stream>>>(P1h, wp2, b2, P2h);
  conv3_mfma<<<dim3(8, 24, 8), 256, 0, stream>>>(P2h, wp3, b3, X3h);
  conv4_mfma<<<dim3(8, 12, 8), 256, 0, stream>>>(X3h, wp4, b4, X4f);
  conv5_res<<<1536, 256, 0, stream>>>(X4f, w5, b5, input, out);
}